// Round 16
// baseline (225.027 us; speedup 1.0000x reference)
//
#include <hip/hip_runtime.h>

#define NB 128
#define NLQ 256   // sequence length L
#define ND 512    // feature dim D
#define NLAYERS 6
#define DD (ND*ND)
#define MN (1024*ND)
#define HTB 131072   // fp16 elems per batch in hT plane: 512*256

typedef _Float16 f16x8 __attribute__((ext_vector_type(8)));
typedef __fp16 fp16x2 __attribute__((ext_vector_type(2)));
typedef _Float16 f16x4v __attribute__((ext_vector_type(4)));
typedef float f32x4 __attribute__((ext_vector_type(4)));
typedef unsigned int u32x2 __attribute__((ext_vector_type(2)));
typedef unsigned int u32x4 __attribute__((ext_vector_type(4)));
typedef unsigned short ushort_t;

#define GLOAD16(gp, lp) __builtin_amdgcn_global_load_lds( \
    (const __attribute__((address_space(1))) void*)(gp), \
    (__attribute__((address_space(3))) void*)(lp), 16, 0, 0)

__device__ __forceinline__ float wave_max(float v){
  #pragma unroll
  for(int off=32; off; off>>=1) v = fmaxf(v, __shfl_xor(v, off));
  return v;
}
__device__ __forceinline__ float wave_sum(float v){
  #pragma unroll
  for(int off=32; off; off>>=1) v += __shfl_xor(v, off);
  return v;
}
// pack two fp32 into one dword of fp16 (v_cvt_pkrtz_f16_f32)
__device__ __forceinline__ unsigned int pk16(float a, float b){
  fp16x2 h = __builtin_amdgcn_cvt_pkrtz(a, b);
  return __builtin_bit_cast(unsigned int, h);
}

__global__ __launch_bounds__(256) void k_scal(const float* __restrict__ a_stack,
                                              float* __restrict__ scal){
  int layer = blockIdx.x;
  const float* a = a_stack + (size_t)layer*2*ND;
  int t = threadIdx.x;
  float v0 = a[t];
  float v1 = a[256 + t];
  v0 = wave_sum(v0); v1 = wave_sum(v1);
  __shared__ float s0[4], s1[4];
  int wave = t>>6, lane = t&63;
  if(lane==0){ s0[wave]=v0; s1[wave]=v1; }
  __syncthreads();
  if(t==0){
    scal[layer*2+0] = s0[0]+s0[1]+s0[2]+s0[3];
    scal[layer*2+1] = s1[0]+s1[1]+s1[2]+s1[3];
  }
}

// v_l[i] = dot(W_{l+1}[i,:], a2_{l+1})
__global__ __launch_bounds__(256) void k_wa2(const float* __restrict__ Wst,
                                             const float* __restrict__ ast,
                                             float* __restrict__ v){
  int l  = blockIdx.x >> 7;
  int rg = blockIdx.x & 127;
  int i  = rg*4 + (threadIdx.x>>6);
  int lane = threadIdx.x & 63;
  const float4* wr = (const float4*)(Wst + (size_t)(l+1)*DD + (size_t)i*ND);
  const float4* ar = (const float4*)(ast + (size_t)(l+1)*2*ND + ND);
  float4 w0=wr[lane], w1=wr[lane+64], a0=ar[lane], a1=ar[lane+64];
  float d = w0.x*a0.x + w0.y*a0.y + w0.z*a0.z + w0.w*a0.w
          + w1.x*a1.x + w1.y*a1.y + w1.z*a1.z + w1.w*a1.w;
  d = wave_sum(d);
  if(lane==0) v[l*ND + i] = d;
}

// transpose + convert W layers to fp16 plane Wt[n][k]. One 64x64 tile per block.
__global__ __launch_bounds__(256) void k_wcvt(const float* __restrict__ Wsrc,
                                              ushort_t* __restrict__ Ho){
  __shared__ float CT[64][65];
  int bid = blockIdx.x;
  int l  = bid >> 6;
  int kt = (bid >> 3) & 7, nt = bid & 7;
  const float* Wl = Wsrc + (size_t)l*DD;
  int t = threadIdx.x;
  int r = t >> 2, c4 = (t&3)*16;
  #pragma unroll
  for(int u=0;u<4;u++){
    float4 vv = *(const float4*)(Wl + (size_t)(kt*64+r)*ND + nt*64 + c4 + u*4);
    CT[r][c4+u*4+0]=vv.x; CT[r][c4+u*4+1]=vv.y;
    CT[r][c4+u*4+2]=vv.z; CT[r][c4+u*4+3]=vv.w;
  }
  __syncthreads();
  int n = t >> 2, kc = t & 3;
  unsigned int o[8];
  #pragma unroll
  for(int j=0;j<8;j++)
    o[j] = pk16(CT[kc*16 + 2*j][n], CT[kc*16 + 2*j + 1][n]);
  ushort_t* dh = Ho + (size_t)l*DD + (size_t)(nt*64+n)*ND + kt*64 + kc*16;
  *(u32x4*)(dh)     = (u32x4){o[0],o[1],o[2],o[3]};
  *(u32x4*)(dh + 8) = (u32x4){o[4],o[5],o[6],o[7]};
}

// xp16 = posw(x) in fp16 (one 16B chunk of 8 elems per thread)
__global__ __launch_bounds__(256) void k_xposw(const float* __restrict__ x,
    ushort_t* __restrict__ xp,
    const int* __restrict__ left, const int* __restrict__ asp, const int* __restrict__ tl){
  int c = blockIdx.x*256 + threadIdx.x;   // 0 .. 2097151
  int row = c >> 6;
  int b = row >> 8;
  float jf = (float)(row & 255);
  float lf=(float)left[b], aspf=(float)asp[b], tlf=(float)tl[b];
  float rr=lf+aspf-1.f, ctx=tlf-aspf;
  float w;
  if(jf < lf)       w = 1.f-(lf-jf)/ctx;
  else if(jf <= rr) w = 0.f;
  else if(jf < tlf) w = 1.f-(jf-rr)/ctx;
  else              w = 0.f;
  const float4* xr = (const float4*)x;
  float4 v0 = xr[(size_t)c*2], v1 = xr[(size_t)c*2+1];
  u32x4 o = (u32x4){ pk16(v0.x*w, v0.y*w), pk16(v0.z*w, v0.w*w),
                     pk16(v1.x*w, v1.y*w), pk16(v1.z*w, v1.w*w) };
  *(u32x4*)(xp + (size_t)c*8) = o;
}

// ---- fp16 MFMA GEMM tile, BK=64, global_load_lds both operands, LDS dbuf ----
// A16 [M][512] fp16, Wt [n][k] fp16. 512 threads (8 waves 2x4), wave tile 64x32.
// MODE=0: C row-major [M][512].
// MODE=1: outputs transposed fp16 plane hP[b][d][i], Pscore fp16, t-partials tp4.
#define BKB 128   // 64 fp16 = 128 B per LDS row
template<int MODE>
__device__ __forceinline__ void gemm_tile(const ushort_t* __restrict__ A16,
                                          const ushort_t* __restrict__ Wth,
                                          float* __restrict__ C,
                                          unsigned int* __restrict__ hP,
                                          ushort_t* __restrict__ Pbuf,
                                          float* __restrict__ tp4,
                                          const float* __restrict__ a2,
                                          const float* __restrict__ scal,
                                          int mtile, int ntile, unsigned char* lds){
  int t = threadIdx.x;                      // 0..511
  int m0 = mtile*128, n0 = ntile*128;
  int lane = t & 63, wid = t >> 6;
  int wr = wid >> 2, wcq = wid & 3;
  int lrow = lane & 15, kb = lane >> 4;

  f32x4 acc[4][2];
  #pragma unroll
  for(int mi=0;mi<4;mi++)
    #pragma unroll
    for(int ni=0;ni<2;ni++)
      acc[mi][ni] = (f32x4){0.f,0.f,0.f,0.f};

  int s_row = t >> 3;       // 0..63
  int s_sl  = t & 7;
  int dstoff = wid*1024;    // wave-uniform; hw adds lane*16

  const ushort_t* Asrc0 = A16 + (size_t)(m0 + s_row)*ND + s_sl*8;
  const ushort_t* Asrc1 = A16 + (size_t)(m0 + 64 + s_row)*ND + s_sl*8;
  const ushort_t* Bsrc0 = Wth + (size_t)(n0 + s_row)*ND + s_sl*8;
  const ushort_t* Bsrc1 = Wth + (size_t)(n0 + 64 + s_row)*ND + s_sl*8;

  // prologue: fill buffer 0
  GLOAD16(Asrc0, lds + dstoff);
  GLOAD16(Asrc1, lds + 8192 + dstoff);
  GLOAD16(Bsrc0, lds + 16384 + dstoff);
  GLOAD16(Bsrc1, lds + 24576 + dstoff);
  __syncthreads();

  int cur = 0;
  for(int it=0; it<8; ++it){
    if(it < 7){
      int kn = (it+1)*64;
      unsigned char* dst = lds + ((cur^1)<<15);
      GLOAD16(Asrc0 + kn, dst + dstoff);
      GLOAD16(Asrc1 + kn, dst + 8192 + dstoff);
      GLOAD16(Bsrc0 + kn, dst + 16384 + dstoff);
      GLOAD16(Bsrc1 + kn, dst + 24576 + dstoff);
    }
    unsigned char* Ab = lds + (cur<<15);
    unsigned char* Bb = Ab + 16384;
    #pragma unroll
    for(int ks=0; ks<2; ks++){
      f16x8 ah[4], bh[2];
      #pragma unroll
      for(int mi=0;mi<4;mi++)
        ah[mi] = *(const f16x8*)(Ab + (wr*64 + mi*16 + lrow)*BKB + ks*64 + kb*16);
      #pragma unroll
      for(int ni=0;ni<2;ni++)
        bh[ni] = *(const f16x8*)(Bb + (wcq*32 + ni*16 + lrow)*BKB + ks*64 + kb*16);
      #pragma unroll
      for(int mi=0;mi<4;mi++)
        #pragma unroll
        for(int ni=0;ni<2;ni++)
          acc[mi][ni] = __builtin_amdgcn_mfma_f32_16x16x32_f16(ah[mi], bh[ni], acc[mi][ni], 0,0,0);
    }
    __syncthreads();
    cur ^= 1;
  }

  int rg = lane >> 4;
  int cc = lane & 15;
  if(MODE == 0){
    #pragma unroll
    for(int mi=0;mi<4;mi++)
      #pragma unroll
      for(int ni=0;ni<2;ni++){
        int col = n0 + wcq*32 + ni*16 + cc;
        #pragma unroll
        for(int q=0;q<4;q++){
          int row = m0 + wr*64 + mi*16 + rg*4 + q;
          C[(size_t)row*ND + col] = acc[mi][ni][q];
        }
      }
  } else {
    float S0 = scal[0], S1 = scal[1];
    float* CT = (float*)lds;   // 64*130 floats = 33280 B (fits 64KB LDS)
    int b = m0 >> 8;
    int ibase = m0 & 255;
    int tr   = t >> 2;
    int tch  = t & 3;
    float tpsum = 0.f;
    #pragma unroll
    for(int p=0;p<2;p++){
      if((wcq>>1) == p){
        #pragma unroll
        for(int mi=0;mi<4;mi++)
          #pragma unroll
          for(int ni=0;ni<2;ni++)
            #pragma unroll
            for(int q=0;q<4;q++)
              CT[((wcq&1)*32 + ni*16 + cc)*130 + wr*64 + mi*16 + rg*4 + q] = acc[mi][ni][q];
      }
      __syncthreads();
      // transposed fp16 plane [b][d][i]
      int lcol = t >> 6;                 // 0..7
      int lrow2 = (t & 63)*2;
      #pragma unroll
      for(int u=0;u<8;u++){
        int c = lcol + u*8;
        float2 v2 = *(float2*)&CT[c*130 + lrow2];
        size_t uidx = ((size_t)b*HTB + (size_t)(n0 + p*64 + c)*256 + ibase + lrow2) >> 1;
        hP[uidx] = pk16(v2.x, v2.y);
      }
      // Pscore fp16 (packed into the (b,itile) h1 region)
      {
        int cpr = t & 31;
        int rq  = t >> 5;                // 0..15
        #pragma unroll
        for(int rr2=0; rr2<8; rr2++){
          int row = rq*8 + rr2;
          float pval = S0*CT[(2*cpr)*130 + row] + S1*CT[(2*cpr+1)*130 + row];
          int ig = ibase + row;
          _Float16 ph = (_Float16)pval;
          size_t addr = (size_t)b*262144 + (size_t)(ig>>5)*32768
                      + (size_t)(ig&31)*256 + (n0>>1) + p*32 + cpr;
          Pbuf[addr] = __builtin_bit_cast(unsigned short, ph);
        }
      }
      // t-partial over this 64-d slab
      #pragma unroll
      for(int cc2=0; cc2<16; cc2++){
        int c = tch*16 + cc2;
        tpsum = fmaf(CT[c*130 + tr], a2[n0 + p*64 + c], tpsum);
      }
      __syncthreads();
    }
    tpsum += __shfl_xor(tpsum, 1);
    tpsum += __shfl_xor(tpsum, 2);
    if(tch == 0) tp4[(n0>>7)*32768 + m0 + tr] = tpsum;
  }
}

__global__ __launch_bounds__(512) void k_gemm_t(const ushort_t* __restrict__ A16,
                                                const ushort_t* __restrict__ Wth,
                                                unsigned int* __restrict__ hP,
                                                ushort_t* __restrict__ Pbuf,
                                                float* __restrict__ tp4,
                                                const float* __restrict__ a2,
                                                const float* __restrict__ scal){
  __shared__ unsigned char lds[65536];
  // XCD swizzle: 4 n-tiles of each m-tile within 32 consecutive bids, all same (bid mod 8)
  int bid = blockIdx.x;
  int ntile = (bid >> 3) & 3;
  int mtile = (bid & 7) | ((bid >> 5) << 3);
  gemm_tile<1>(A16, Wth, nullptr, hP, Pbuf, tp4, a2, scal, mtile, ntile, lds);
}

__global__ __launch_bounds__(512) void k_gemm_b(const ushort_t* __restrict__ Abase, long aStride,
                                                const ushort_t* __restrict__ Wth,
                                                float* __restrict__ Cbase){
  __shared__ unsigned char lds[65536];
  int l  = blockIdx.x >> 5;
  int tb = blockIdx.x & 31;
  gemm_tile<0>(Abase + (size_t)l*aStride, Wth + (size_t)l*DD,
               Cbase + (size_t)l*MN, nullptr, nullptr, nullptr,
               nullptr, nullptr, tb>>2, tb&3, lds);
}

// layer-0 attention: coalesced fp16-P softmax (lanes=j, adj direct int4)
// + MFMA aggregation (att fp16, h plane fp16) with global_load_lds B staging.
__global__ __launch_bounds__(256) void k_attn0(
    const ushort_t* __restrict__ hTH,
    const int* __restrict__ adj,
    const float* __restrict__ tpart,
    const int* __restrict__ left, const int* __restrict__ asp, const int* __restrict__ tl,
    float* __restrict__ PA){
  __shared__ unsigned char attH[32*512];   // fp16 att [32 i][256 j], XOR-swizzled
  __shared__ unsigned char BsH[16384];     // staged fp16 plane [256 d][32 j] linear 64B rows

  int bid = blockIdx.x;
  int b  = bid & 127;      // 8 blocks of batch b land on same XCD
  int ic = bid >> 7;
  int i0 = ic*32;
  int tid = threadIdx.x;
  int lane = tid & 63, w = tid >> 6;
  const ushort_t* HH = hTH + (size_t)b*HTB;
  const ushort_t* Pt = (const ushort_t*)PA + (size_t)b*262144 + (size_t)ic*32768;

  // ---- phase 1: softmax, lanes = j (4 j's per lane) ----
  float t0v=0.f, t1v=0.f, t2v=0.f, t3v=0.f;
  #pragma unroll
  for(int nt=0; nt<4; nt++){
    float4 tv = ((const float4*)(tpart + nt*32768 + b*256))[lane];
    t0v += tv.x; t1v += tv.y; t2v += tv.z; t3v += tv.w;
  }

  for(int rr=0; rr<8; rr++){
    int il = w*8 + rr;         // 0..31
    int i  = i0 + il;
    f16x4v pv = *(const f16x4v*)(Pt + il*256 + lane*4);
    int4 av = ((const int4*)(adj + ((size_t)b*NLQ + i)*NLQ))[lane];
    float e0 = fmaxf((float)pv[0] + t0v, 0.f);
    float e1 = fmaxf((float)pv[1] + t1v, 0.f);
    float e2 = fmaxf((float)pv[2] + t2v, 0.f);
    float e3 = fmaxf((float)pv[3] + t3v, 0.f);
    float m = -3.0e38f;
    if(av.x>0) m = e0;
    if(av.y>0) m = fmaxf(m, e1);
    if(av.z>0) m = fmaxf(m, e2);
    if(av.w>0) m = fmaxf(m, e3);
    m = wave_max(m);
    float p0 = (av.x>0) ? __expf(e0-m) : 0.f;
    float p1 = (av.y>0) ? __expf(e1-m) : 0.f;
    float p2 = (av.z>0) ? __expf(e2-m) : 0.f;
    float p3 = (av.w>0) ? __expf(e3-m) : 0.f;
    float s = wave_sum(p0+p1+p2+p3);
    float inv = 1.f/s;
    unsigned int w0 = pk16(p0*inv, p1*inv);
    unsigned int w1 = pk16(p2*inv, p3*inv);
    int off = il*512 + ((lane*8) ^ ((il&7)<<4));
    *(u32x2*)(attH + off) = (u32x2){w0,w1};
  }

  // ---- phase 2: O[i][d] = att @ h via MFMA; B staged via global_load_lds ----
  int wm = w >> 1, wn = w & 1;
  int lrow = lane & 15, kb = lane >> 4;
  int rg = lane >> 4, cc = lane & 15;
  float lf=(float)left[b], aspf=(float)asp[b], tlf=(float)tl[b];
  float rrv=lf+aspf-1.f, ctx=tlf-aspf;
  int arow = wm*16 + lrow;
  int aswz = (arow&7)<<4;

  for(int dp=0; dp<2; dp++){
    int d0 = dp*256;
    f32x4 acc[8];
    #pragma unroll
    for(int ni=0;ni<8;ni++) acc[ni] = (f32x4){0.f,0.f,0.f,0.f};
    for(int ks=0; ks<8; ks++){
      int j0 = ks*32;
      __syncthreads();   // previous tile fully consumed (also orders att writes)
      #pragma unroll
      for(int u=0;u<4;u++){
        int chunk = (u*4 + w)*64 + lane;
        int row = chunk >> 2, sl = chunk & 3;
        GLOAD16(HH + (size_t)(d0+row)*256 + j0 + sl*8, BsH + (u*4+w)*1024);
      }
      __syncthreads();   // loads landed
      int aoff = arow*512 + ((j0*2 + kb*16) ^ aswz);
      f16x8 ah = *(const f16x8*)(attH + aoff);
      #pragma unroll
      for(int ni=0; ni<8; ni++){
        f16x8 bh = *(const f16x8*)(BsH + (wn*128 + ni*16 + lrow)*64 + kb*16);
        acc[ni] = __builtin_amdgcn_mfma_f32_16x16x32_f16(ah, bh, acc[ni], 0,0,0);
      }
    }
    #pragma unroll
    for(int q=0;q<4;q++){
      int row = i0 + wm*16 + rg*4 + q;
      float fi = (float)row;
      float wgt;
      if(fi < lf)        wgt = 1.f-(lf-fi)/ctx;
      else if(fi <= rrv) wgt = 0.f;
      else if(fi < tlf)  wgt = 1.f-(fi-rrv)/ctx;
      else               wgt = 0.f;
      #pragma unroll
      for(int ni=0;ni<8;ni++){
        int col = d0 + wn*128 + ni*16 + cc;
        PA[((size_t)b*NLQ + row)*ND + col] = wgt*fmaxf(acc[ni][q], 0.f);
      }
    }
  }
}

// T[l][b*256+j] = h1[b,j,:] . v_l
__global__ __launch_bounds__(256) void k_tv(const float* __restrict__ h1,
                                            const float* __restrict__ v,
                                            float* __restrict__ T){
  int row  = blockIdx.x*4 + (threadIdx.x>>6);
  int lane = threadIdx.x & 63;
  const float4* hr = (const float4*)(h1 + (size_t)row*ND);
  float4 h0 = hr[lane], h1v = hr[lane+64];
  float s0,s1,s2,s3,s4;
  #define DOTV(SL, L) { \
    const float4* vr = (const float4*)(v + (L)*ND); \
    float4 v0 = vr[lane], v1 = vr[lane+64]; \
    float dd = h0.x*v0.x+h0.y*v0.y+h0.z*v0.z+h0.w*v0.w \
             + h1v.x*v1.x+h1v.y*v1.y+h1v.z*v1.z+h1v.w*v1.w; \
    SL = wave_sum(dd); }
  DOTV(s0,0) DOTV(s1,1) DOTV(s2,2) DOTV(s3,3) DOTV(s4,4)
  #undef DOTV
  if(lane==0){
    T[0*32768 + row]=s0; T[1*32768 + row]=s1; T[2*32768 + row]=s2;
    T[3*32768 + row]=s3; T[4*32768 + row]=s4;
  }
}

// R16[b*8+k,:] = fp16(h1[b, l0+k, :]) or 0
__global__ __launch_bounds__(256) void k_rows(const float* __restrict__ h1,
                                              const int* __restrict__ left, const int* __restrict__ asp,
                                              ushort_t* __restrict__ R){
  int b = blockIdx.x;
  int nk = asp[b], l0 = left[b];
  const float* src = h1 + (size_t)b*NLQ*ND;
  unsigned int* dst = (unsigned int*)(R + (size_t)b*8*ND);
  #pragma unroll
  for(int u=0; u<8; u++){
    int idx = threadIdx.x + u*256;     // 0..2047 u32
    int k = idx >> 8, c = idx & 255;
    float2 vv = (k<nk) ? ((const float2*)(src + (size_t)(l0+k)*ND))[c] : (float2){0.f,0.f};
    dst[idx] = pk16(vv.x, vv.y);
  }
}

// one block per (layer, batch): 5 aspect-row atts + y16 = fp16(att @ h1).
__global__ __launch_bounds__(256) void k_att5(const float* __restrict__ h1,
    const float* __restrict__ Hasp, const float* __restrict__ T,
    const int* __restrict__ adj, const float* __restrict__ scal,
    const int* __restrict__ left, const int* __restrict__ asp,
    ushort_t* __restrict__ y){
  __shared__ float att[5][260];
  int b  = blockIdx.x & 127;
  int l  = blockIdx.x >> 7;
  int tid = threadIdx.x, lane = tid&63, w = tid>>6;
  int nk = asp[b], l0 = left[b];
  float S0 = scal[2*(l+1)], S1 = scal[2*(l+1)+1];

  for(int k = w; k < 5; k += 4){
    if(k < nk){
      const float2* hrow = (const float2*)(Hasp + (size_t)l*MN + (size_t)(b*8+k)*ND);
      const int* arow = adj + ((size_t)b*NLQ + (l0+k))*NLQ;
      const float* Tl = T + l*32768 + b*256;
      float e[4]; int av[4];
      float m = -3.0e38f;
      #pragma unroll
      for(int q=0;q<4;q++){
        int j = lane + 64*q;
        float2 hp = hrow[j];
        av[q] = arow[j];
        e[q] = fmaxf(S0*hp.x + S1*hp.y + Tl[j], 0.f);
        if(av[q] > 0) m = fmaxf(m, e[q]);
      }
      m = wave_max(m);
      float pp[4]; float s = 0.f;
      #pragma unroll
      for(int q=0;q<4;q++){
        pp[q] = (av[q] > 0) ? __expf(e[q]-m) : 0.f;
        s += pp[q];
      }
      s = wave_sum(s);
      float inv = 1.f/s;
      #pragma unroll
      for(int q=0;q<4;q++) att[k][lane+64*q] = pp[q]*inv;
    } else {
      #pragma unroll
      for(int q=0;q<4;q++) att[k][lane+64*q] = 0.f;
    }
  }
  __syncthreads();

  int d = tid;
  const float* hb = h1 + (size_t)b*NLQ*ND;
  float ax[5] = {0,0,0,0,0}, ay[5] = {0,0,0,0,0};
  for(int jj=0; jj<NLQ; jj++){
    float hx = hb[(size_t)jj*ND + d];
    float hy = hb[(size_t)jj*ND + 256 + d];
    #pragma unroll
    for(int k=0;k<5;k++){
      float a = att[k][jj];
      ax[k] += a*hx;
      ay[k] += a*hy;
    }
  }
  ushort_t* yb = y + (size_t)l*MN + (size_t)b*8*ND;
  #pragma unroll
  for(int k=0;k<5;k++){
    yb[(size_t)k*ND + d]       = __builtin_bit_cast(unsigned short, (_Float16)ax[k]);
    yb[(size_t)k*ND + 256 + d] = __builtin_bit_cast(unsigned short, (_Float16)ay[k]);
  }
  #pragma unroll
  for(int u=0;u<6;u++) yb[5*ND + u*256 + tid] = 0;
}

__global__ __launch_bounds__(256) void k_g(const float* __restrict__ hp,
    const int* __restrict__ asp, float* __restrict__ g){
  int b = blockIdx.x, d = threadIdx.x;
  int nk = asp[b];
  float gx=0.f, gy=0.f;
  for(int l=0;l<5;l++){
    for(int k=0;k<nk;k++){
      const float* r = hp + (size_t)l*MN + (size_t)(b*8+k)*ND;
      gx += fmaxf(r[d], 0.f);
      gy += fmaxf(r[d+256], 0.f);
    }
  }
  g[b*ND + d]       = 0.2f*gx;
  g[b*ND + 256 + d] = 0.2f*gy;
}

__global__ __launch_bounds__(256) void k_dot(const float* __restrict__ x,
    const float* __restrict__ g, float* __restrict__ s){
  int row  = blockIdx.x*4 + (threadIdx.x>>6);
  int b    = row >> 8;
  int lane = threadIdx.x & 63;
  const float4* xr = (const float4*)(x + (size_t)row*ND);
  const float4* gr = (const float4*)(g + (size_t)b*ND);
  float4 x0=xr[lane], x1=xr[lane+64], g0=gr[lane], g1=gr[lane+64];
  float d = x0.x*g0.x + x0.y*g0.y + x0.z*g0.z + x0.w*g0.w
          + x1.x*g1.x + x1.y*g1.y + x1.z*g1.z + x1.w*g1.w;
  d = wave_sum(d);
  if(lane==0) s[row] = d;
}

__global__ __launch_bounds__(256) void k_out(const float* __restrict__ x,
    const float* __restrict__ s, float* __restrict__ out){
  int b  = blockIdx.x >> 2;
  int ch = blockIdx.x & 3;
  int tid = threadIdx.x, lane = tid&63, w = tid>>6;
  __shared__ float red[4];
  __shared__ float alpha[NLQ];
  __shared__ float part[128];
  float sv = s[b*NLQ + tid];
  float m = wave_max(sv);
  if(lane==0) red[w] = m;
  __syncthreads();
  m = fmaxf(fmaxf(red[0],red[1]), fmaxf(red[2],red[3]));
  float p = __expf(sv - m);
  float su = wave_sum(p);
  __syncthreads();
  if(lane==0) red[w] = su;
  __syncthreads();
  su = red[0]+red[1]+red[2]+red[3];
  alpha[tid] = p/su;
  __syncthreads();
  int d = ch*128 + (tid & 127);
  int half = tid >> 7;
  const float* xb = x + (size_t)b*NLQ*ND;
  float acc = 0.f;
  for(int mm = half*128; mm < half*128 + 128; mm++)
    acc += alpha[mm] * xb[(size_t)mm*ND + d];
  if(half) part[tid & 127] = acc;
  __syncthreads();
  if(!half) out[(size_t)b*ND + d] = acc + part[tid & 127];
}

extern "C" void kernel_launch(void* const* d_in, const int* in_sizes, int n_in,
                              void* d_out, int out_size, void* d_ws, size_t ws_size,
                              hipStream_t stream){
  const float* x    = (const float*)d_in[0];
  const float* Wst  = (const float*)d_in[1];
  const float* ast  = (const float*)d_in[2];
  const int*   adj  = (const int*)d_in[3];
  const int*   left = (const int*)d_in[4];
  const int*   asp  = (const int*)d_in[5];
  const int*   tl   = (const int*)d_in[6];
  float* out = (float*)d_out;
  float* ws  = (float*)d_ws;

  const size_t SZ = (size_t)NB*NLQ*ND;
  float* bufA = ws;                     // P (fp16, packed per tile) -> h1
  float* bufB = ws + SZ;                // [0..8.39M): hT plane; [8.39M..16.78M): xp16
  float* ws2  = ws + 2*SZ;
  float* tpart= ws2;                    // 4*32768
  float* T    = tpart + 4*32768;        // 163840
  float* g    = T + 163840;             // 65536
  float* scal = g + 65536;              // 16
  float* v    = scal + 16;              // 2560
  float* sbuf = v + 2560;               // 32768
  ushort_t* w0th = (ushort_t*)(sbuf + 32768);  // DD ushorts (layer-0 Wt fp16)

  ushort_t* hTH  = (ushort_t*)bufB;                  // NB*HTB fp16
  ushort_t* xp16 = (ushort_t*)(bufB + (SZ>>1));      // NB*NLQ*ND fp16 (dead after k_gemm_t)

  float* Hasp = bufB;                   // reuse after k_attn0
  ushort_t* y16 = (ushort_t*)(Hasp + (size_t)5*MN);  // 5*MN fp16 (uses half the old slot)
  float* hp   = Hasp + (size_t)10*MN;
  ushort_t* R16 = (ushort_t*)(hp + (size_t)5*MN);    // 1024*ND fp16
  ushort_t* wt15h = (ushort_t*)(hp + (size_t)5*MN + (MN>>1));  // 5*DD ushorts

  k_scal<<<NLAYERS, 256, 0, stream>>>(ast, scal);
  k_wa2<<<5*128, 256, 0, stream>>>(Wst, ast, v);
  k_wcvt<<<64, 256, 0, stream>>>(Wst, w0th);
  k_xposw<<<8192, 256, 0, stream>>>(x, xp16, left, asp, tl);

  // layer 0: pure fp16 GEMM (gload_lds both sides); emits plane + P + t-partials
  k_gemm_t<<<(NB*NLQ/128)*(ND/128), 512, 0, stream>>>(xp16, w0th,
      (unsigned int*)hTH, (ushort_t*)bufA, tpart, ast + ND, scal);
  k_attn0<<<NB*8, 256, 0, stream>>>(hTH, adj, tpart, left, asp, tl, bufA);

  // layers 1..5 on aspect rows only
  k_wcvt<<<5*64, 256, 0, stream>>>(Wst + DD, wt15h);
  k_tv<<<NB*NLQ/4, 256, 0, stream>>>(bufA, v, T);
  k_rows<<<NB, 256, 0, stream>>>(bufA, left, asp, R16);
  k_gemm_b<<<5*32, 512, 0, stream>>>(R16, 0L, wt15h, Hasp);
  k_att5<<<5*NB, 256, 0, stream>>>(bufA, Hasp, T, adj, scal, left, asp, y16);
  k_gemm_b<<<5*32, 512, 0, stream>>>(y16, (long)MN, wt15h, hp);
  k_g<<<NB, 256, 0, stream>>>(hp, asp, g);

  // final attention over original x
  k_dot<<<NB*NLQ/4, 256, 0, stream>>>(x, g, sbuf);
  k_out<<<NB*4, 256, 0, stream>>>(x, sbuf, out);
}

// Round 17
// 218.821 us; speedup vs baseline: 1.0284x; 1.0284x over previous
//
#include <hip/hip_runtime.h>

#define NB 128
#define NLQ 256   // sequence length L
#define ND 512    // feature dim D
#define NLAYERS 6
#define DD (ND*ND)
#define MN (1024*ND)
#define HTB 131072   // fp16 elems per batch in hT plane: 512*256

typedef _Float16 f16x8 __attribute__((ext_vector_type(8)));
typedef __fp16 fp16x2 __attribute__((ext_vector_type(2)));
typedef _Float16 f16x4v __attribute__((ext_vector_type(4)));
typedef float f32x4 __attribute__((ext_vector_type(4)));
typedef unsigned int u32x2 __attribute__((ext_vector_type(2)));
typedef unsigned int u32x4 __attribute__((ext_vector_type(4)));
typedef unsigned short ushort_t;

#define GLOAD16(gp, lp) __builtin_amdgcn_global_load_lds( \
    (const __attribute__((address_space(1))) void*)(gp), \
    (__attribute__((address_space(3))) void*)(lp), 16, 0, 0)

__device__ __forceinline__ float wave_max(float v){
  #pragma unroll
  for(int off=32; off; off>>=1) v = fmaxf(v, __shfl_xor(v, off));
  return v;
}
__device__ __forceinline__ float wave_sum(float v){
  #pragma unroll
  for(int off=32; off; off>>=1) v += __shfl_xor(v, off);
  return v;
}
// pack two fp32 into one dword of fp16 (v_cvt_pkrtz_f16_f32)
__device__ __forceinline__ unsigned int pk16(float a, float b){
  fp16x2 h = __builtin_amdgcn_cvt_pkrtz(a, b);
  return __builtin_bit_cast(unsigned int, h);
}

__global__ __launch_bounds__(256) void k_scal(const float* __restrict__ a_stack,
                                              float* __restrict__ scal){
  int layer = blockIdx.x;
  const float* a = a_stack + (size_t)layer*2*ND;
  int t = threadIdx.x;
  float v0 = a[t];
  float v1 = a[256 + t];
  v0 = wave_sum(v0); v1 = wave_sum(v1);
  __shared__ float s0[4], s1[4];
  int wave = t>>6, lane = t&63;
  if(lane==0){ s0[wave]=v0; s1[wave]=v1; }
  __syncthreads();
  if(t==0){
    scal[layer*2+0] = s0[0]+s0[1]+s0[2]+s0[3];
    scal[layer*2+1] = s1[0]+s1[1]+s1[2]+s1[3];
  }
}

// v_l[i] = dot(W_{l+1}[i,:], a2_{l+1})
__global__ __launch_bounds__(256) void k_wa2(const float* __restrict__ Wst,
                                             const float* __restrict__ ast,
                                             float* __restrict__ v){
  int l  = blockIdx.x >> 7;
  int rg = blockIdx.x & 127;
  int i  = rg*4 + (threadIdx.x>>6);
  int lane = threadIdx.x & 63;
  const float4* wr = (const float4*)(Wst + (size_t)(l+1)*DD + (size_t)i*ND);
  const float4* ar = (const float4*)(ast + (size_t)(l+1)*2*ND + ND);
  float4 w0=wr[lane], w1=wr[lane+64], a0=ar[lane], a1=ar[lane+64];
  float d = w0.x*a0.x + w0.y*a0.y + w0.z*a0.z + w0.w*a0.w
          + w1.x*a1.x + w1.y*a1.y + w1.z*a1.z + w1.w*a1.w;
  d = wave_sum(d);
  if(lane==0) v[l*ND + i] = d;
}

// transpose + convert W layers to fp16 plane Wt[n][k]. One 64x64 tile per block.
__global__ __launch_bounds__(256) void k_wcvt(const float* __restrict__ Wsrc,
                                              ushort_t* __restrict__ Ho){
  __shared__ float CT[64][65];
  int bid = blockIdx.x;
  int l  = bid >> 6;
  int kt = (bid >> 3) & 7, nt = bid & 7;
  const float* Wl = Wsrc + (size_t)l*DD;
  int t = threadIdx.x;
  int r = t >> 2, c4 = (t&3)*16;
  #pragma unroll
  for(int u=0;u<4;u++){
    float4 vv = *(const float4*)(Wl + (size_t)(kt*64+r)*ND + nt*64 + c4 + u*4);
    CT[r][c4+u*4+0]=vv.x; CT[r][c4+u*4+1]=vv.y;
    CT[r][c4+u*4+2]=vv.z; CT[r][c4+u*4+3]=vv.w;
  }
  __syncthreads();
  int n = t >> 2, kc = t & 3;
  unsigned int o[8];
  #pragma unroll
  for(int j=0;j<8;j++)
    o[j] = pk16(CT[kc*16 + 2*j][n], CT[kc*16 + 2*j + 1][n]);
  ushort_t* dh = Ho + (size_t)l*DD + (size_t)(nt*64+n)*ND + kt*64 + kc*16;
  *(u32x4*)(dh)     = (u32x4){o[0],o[1],o[2],o[3]};
  *(u32x4*)(dh + 8) = (u32x4){o[4],o[5],o[6],o[7]};
}

// xp16 = posw(x) in fp16 (one 16B chunk of 8 elems per thread)
__global__ __launch_bounds__(256) void k_xposw(const float* __restrict__ x,
    ushort_t* __restrict__ xp,
    const int* __restrict__ left, const int* __restrict__ asp, const int* __restrict__ tl){
  int c = blockIdx.x*256 + threadIdx.x;   // 0 .. 2097151
  int row = c >> 6;
  int b = row >> 8;
  float jf = (float)(row & 255);
  float lf=(float)left[b], aspf=(float)asp[b], tlf=(float)tl[b];
  float rr=lf+aspf-1.f, ctx=tlf-aspf;
  float w;
  if(jf < lf)       w = 1.f-(lf-jf)/ctx;
  else if(jf <= rr) w = 0.f;
  else if(jf < tlf) w = 1.f-(jf-rr)/ctx;
  else              w = 0.f;
  const float4* xr = (const float4*)x;
  float4 v0 = xr[(size_t)c*2], v1 = xr[(size_t)c*2+1];
  u32x4 o = (u32x4){ pk16(v0.x*w, v0.y*w), pk16(v0.z*w, v0.w*w),
                     pk16(v1.x*w, v1.y*w), pk16(v1.z*w, v1.w*w) };
  *(u32x4*)(xp + (size_t)c*8) = o;
}

// ---- fp16 MFMA GEMM tile, BK=64, global_load_lds both operands, LDS dbuf,
// XOR-swizzled (slot ^= row&7 over 16B units, pre-swizzled global source) ----
// A16 [M][512] fp16, Wt [n][k] fp16. 512 threads (8 waves 2x4), wave tile 64x32.
// MODE=0: C row-major [M][512].
// MODE=1: outputs transposed fp16 plane hP[b][d][i], Pscore fp16, t-partials tp4.
#define BKB 128   // 64 fp16 = 128 B per LDS row (8 x 16B slots)
template<int MODE>
__device__ __forceinline__ void gemm_tile(const ushort_t* __restrict__ A16,
                                          const ushort_t* __restrict__ Wth,
                                          float* __restrict__ C,
                                          unsigned int* __restrict__ hP,
                                          ushort_t* __restrict__ Pbuf,
                                          float* __restrict__ tp4,
                                          const float* __restrict__ a2,
                                          const float* __restrict__ scal,
                                          int mtile, int ntile, unsigned char* lds){
  int t = threadIdx.x;                      // 0..511
  int m0 = mtile*128, n0 = ntile*128;
  int lane = t & 63, wid = t >> 6;
  int wr = wid >> 2, wcq = wid & 3;
  int lrow = lane & 15, kb = lane >> 4;

  f32x4 acc[4][2];
  #pragma unroll
  for(int mi=0;mi<4;mi++)
    #pragma unroll
    for(int ni=0;ni<2;ni++)
      acc[mi][ni] = (f32x4){0.f,0.f,0.f,0.f};

  int s_row = t >> 3;                 // 0..63
  int s_sl  = (t & 7) ^ (s_row & 7);  // pre-swizzled source slot
  int dstoff = wid*1024;              // wave-uniform; hw adds lane*16

  const ushort_t* Asrc0 = A16 + (size_t)(m0 + s_row)*ND + s_sl*8;
  const ushort_t* Asrc1 = A16 + (size_t)(m0 + 64 + s_row)*ND + s_sl*8;
  const ushort_t* Bsrc0 = Wth + (size_t)(n0 + s_row)*ND + s_sl*8;
  const ushort_t* Bsrc1 = Wth + (size_t)(n0 + 64 + s_row)*ND + s_sl*8;

  // prologue: fill buffer 0
  GLOAD16(Asrc0, lds + dstoff);
  GLOAD16(Asrc1, lds + 8192 + dstoff);
  GLOAD16(Bsrc0, lds + 16384 + dstoff);
  GLOAD16(Bsrc1, lds + 24576 + dstoff);
  __syncthreads();

  int cur = 0;
  for(int it=0; it<8; ++it){
    if(it < 7){
      int kn = (it+1)*64;
      unsigned char* dst = lds + ((cur^1)<<15);
      GLOAD16(Asrc0 + kn, dst + dstoff);
      GLOAD16(Asrc1 + kn, dst + 8192 + dstoff);
      GLOAD16(Bsrc0 + kn, dst + 16384 + dstoff);
      GLOAD16(Bsrc1 + kn, dst + 24576 + dstoff);
    }
    unsigned char* Ab = lds + (cur<<15);
    unsigned char* Bb = Ab + 16384;
    #pragma unroll
    for(int ks=0; ks<2; ks++){
      f16x8 ah[4], bh[2];
      #pragma unroll
      for(int mi=0;mi<4;mi++){
        int ar = wr*64 + mi*16 + lrow;
        int sl = (ks*4 + kb) ^ (ar & 7);
        ah[mi] = *(const f16x8*)(Ab + ar*BKB + sl*16);
      }
      #pragma unroll
      for(int ni=0;ni<2;ni++){
        int br = wcq*32 + ni*16 + lrow;
        int sl = (ks*4 + kb) ^ (br & 7);
        bh[ni] = *(const f16x8*)(Bb + br*BKB + sl*16);
      }
      #pragma unroll
      for(int mi=0;mi<4;mi++)
        #pragma unroll
        for(int ni=0;ni<2;ni++)
          acc[mi][ni] = __builtin_amdgcn_mfma_f32_16x16x32_f16(ah[mi], bh[ni], acc[mi][ni], 0,0,0);
    }
    __syncthreads();
    cur ^= 1;
  }

  int rg = lane >> 4;
  int cc = lane & 15;
  if(MODE == 0){
    #pragma unroll
    for(int mi=0;mi<4;mi++)
      #pragma unroll
      for(int ni=0;ni<2;ni++){
        int col = n0 + wcq*32 + ni*16 + cc;
        #pragma unroll
        for(int q=0;q<4;q++){
          int row = m0 + wr*64 + mi*16 + rg*4 + q;
          C[(size_t)row*ND + col] = acc[mi][ni][q];
        }
      }
  } else {
    float S0 = scal[0], S1 = scal[1];
    float* CT = (float*)lds;   // 64*130 floats = 33280 B (fits 64KB LDS)
    int b = m0 >> 8;
    int ibase = m0 & 255;
    int tr   = t >> 2;
    int tch  = t & 3;
    float tpsum = 0.f;
    #pragma unroll
    for(int p=0;p<2;p++){
      if((wcq>>1) == p){
        #pragma unroll
        for(int mi=0;mi<4;mi++)
          #pragma unroll
          for(int ni=0;ni<2;ni++)
            #pragma unroll
            for(int q=0;q<4;q++)
              CT[((wcq&1)*32 + ni*16 + cc)*130 + wr*64 + mi*16 + rg*4 + q] = acc[mi][ni][q];
      }
      __syncthreads();
      // transposed fp16 plane [b][d][i]
      int lcol = t >> 6;                 // 0..7
      int lrow2 = (t & 63)*2;
      #pragma unroll
      for(int u=0;u<8;u++){
        int c = lcol + u*8;
        float2 v2 = *(float2*)&CT[c*130 + lrow2];
        size_t uidx = ((size_t)b*HTB + (size_t)(n0 + p*64 + c)*256 + ibase + lrow2) >> 1;
        hP[uidx] = pk16(v2.x, v2.y);
      }
      // Pscore fp16 (packed into the (b,itile) h1 region)
      {
        int cpr = t & 31;
        int rq  = t >> 5;                // 0..15
        #pragma unroll
        for(int rr2=0; rr2<8; rr2++){
          int row = rq*8 + rr2;
          float pval = S0*CT[(2*cpr)*130 + row] + S1*CT[(2*cpr+1)*130 + row];
          int ig = ibase + row;
          _Float16 ph = (_Float16)pval;
          size_t addr = (size_t)b*262144 + (size_t)(ig>>5)*32768
                      + (size_t)(ig&31)*256 + (n0>>1) + p*32 + cpr;
          Pbuf[addr] = __builtin_bit_cast(unsigned short, ph);
        }
      }
      // t-partial over this 64-d slab
      #pragma unroll
      for(int cc2=0; cc2<16; cc2++){
        int c = tch*16 + cc2;
        tpsum = fmaf(CT[c*130 + tr], a2[n0 + p*64 + c], tpsum);
      }
      __syncthreads();
    }
    tpsum += __shfl_xor(tpsum, 1);
    tpsum += __shfl_xor(tpsum, 2);
    if(tch == 0) tp4[(n0>>7)*32768 + m0 + tr] = tpsum;
  }
}

__global__ __launch_bounds__(512) void k_gemm_t(const ushort_t* __restrict__ A16,
                                                const ushort_t* __restrict__ Wth,
                                                unsigned int* __restrict__ hP,
                                                ushort_t* __restrict__ Pbuf,
                                                float* __restrict__ tp4,
                                                const float* __restrict__ a2,
                                                const float* __restrict__ scal){
  __shared__ unsigned char lds[65536];
  // XCD swizzle: 4 n-tiles of each m-tile within 32 consecutive bids, all same (bid mod 8)
  int bid = blockIdx.x;
  int ntile = (bid >> 3) & 3;
  int mtile = (bid & 7) | ((bid >> 5) << 3);
  gemm_tile<1>(A16, Wth, nullptr, hP, Pbuf, tp4, a2, scal, mtile, ntile, lds);
}

__global__ __launch_bounds__(512) void k_gemm_b(const ushort_t* __restrict__ Abase, long aStride,
                                                const ushort_t* __restrict__ Wth,
                                                float* __restrict__ Cbase){
  __shared__ unsigned char lds[65536];
  int l  = blockIdx.x >> 5;
  int tb = blockIdx.x & 31;
  gemm_tile<0>(Abase + (size_t)l*aStride, Wth + (size_t)l*DD,
               Cbase + (size_t)l*MN, nullptr, nullptr, nullptr,
               nullptr, nullptr, tb>>2, tb&3, lds);
}

// layer-0 attention: coalesced fp16-P softmax (lanes=j, adj direct int4)
// + MFMA aggregation (att fp16, h plane fp16) with global_load_lds B staging.
__global__ __launch_bounds__(256) void k_attn0(
    const ushort_t* __restrict__ hTH,
    const int* __restrict__ adj,
    const float* __restrict__ tpart,
    const int* __restrict__ left, const int* __restrict__ asp, const int* __restrict__ tl,
    float* __restrict__ PA){
  __shared__ unsigned char attH[32*512];   // fp16 att [32 i][256 j], XOR-swizzled
  __shared__ unsigned char BsH[16384];     // staged fp16 plane [256 d][32 j] linear 64B rows

  int bid = blockIdx.x;
  int b  = bid & 127;      // 8 blocks of batch b land on same XCD
  int ic = bid >> 7;
  int i0 = ic*32;
  int tid = threadIdx.x;
  int lane = tid & 63, w = tid >> 6;
  const ushort_t* HH = hTH + (size_t)b*HTB;
  const ushort_t* Pt = (const ushort_t*)PA + (size_t)b*262144 + (size_t)ic*32768;

  // ---- phase 1: softmax, lanes = j (4 j's per lane) ----
  float t0v=0.f, t1v=0.f, t2v=0.f, t3v=0.f;
  #pragma unroll
  for(int nt=0; nt<4; nt++){
    float4 tv = ((const float4*)(tpart + nt*32768 + b*256))[lane];
    t0v += tv.x; t1v += tv.y; t2v += tv.z; t3v += tv.w;
  }

  for(int rr=0; rr<8; rr++){
    int il = w*8 + rr;         // 0..31
    int i  = i0 + il;
    f16x4v pv = *(const f16x4v*)(Pt + il*256 + lane*4);
    int4 av = ((const int4*)(adj + ((size_t)b*NLQ + i)*NLQ))[lane];
    float e0 = fmaxf((float)pv[0] + t0v, 0.f);
    float e1 = fmaxf((float)pv[1] + t1v, 0.f);
    float e2 = fmaxf((float)pv[2] + t2v, 0.f);
    float e3 = fmaxf((float)pv[3] + t3v, 0.f);
    float m = -3.0e38f;
    if(av.x>0) m = e0;
    if(av.y>0) m = fmaxf(m, e1);
    if(av.z>0) m = fmaxf(m, e2);
    if(av.w>0) m = fmaxf(m, e3);
    m = wave_max(m);
    float p0 = (av.x>0) ? __expf(e0-m) : 0.f;
    float p1 = (av.y>0) ? __expf(e1-m) : 0.f;
    float p2 = (av.z>0) ? __expf(e2-m) : 0.f;
    float p3 = (av.w>0) ? __expf(e3-m) : 0.f;
    float s = wave_sum(p0+p1+p2+p3);
    float inv = 1.f/s;
    unsigned int w0 = pk16(p0*inv, p1*inv);
    unsigned int w1 = pk16(p2*inv, p3*inv);
    int off = il*512 + ((lane*8) ^ ((il&7)<<4));
    *(u32x2*)(attH + off) = (u32x2){w0,w1};
  }

  // ---- phase 2: O[i][d] = att @ h via MFMA; B staged via global_load_lds ----
  int wm = w >> 1, wn = w & 1;
  int lrow = lane & 15, kb = lane >> 4;
  int rg = lane >> 4, cc = lane & 15;
  float lf=(float)left[b], aspf=(float)asp[b], tlf=(float)tl[b];
  float rrv=lf+aspf-1.f, ctx=tlf-aspf;
  int arow = wm*16 + lrow;
  int aswz = (arow&7)<<4;

  for(int dp=0; dp<2; dp++){
    int d0 = dp*256;
    f32x4 acc[8];
    #pragma unroll
    for(int ni=0;ni<8;ni++) acc[ni] = (f32x4){0.f,0.f,0.f,0.f};
    for(int ks=0; ks<8; ks++){
      int j0 = ks*32;
      __syncthreads();   // previous tile fully consumed (also orders att writes)
      #pragma unroll
      for(int u=0;u<4;u++){
        int chunk = (u*4 + w)*64 + lane;
        int row = chunk >> 2, sl = chunk & 3;
        GLOAD16(HH + (size_t)(d0+row)*256 + j0 + sl*8, BsH + (u*4+w)*1024);
      }
      __syncthreads();   // loads landed
      int aoff = arow*512 + ((j0*2 + kb*16) ^ aswz);
      f16x8 ah = *(const f16x8*)(attH + aoff);
      #pragma unroll
      for(int ni=0; ni<8; ni++){
        f16x8 bh = *(const f16x8*)(BsH + (wn*128 + ni*16 + lrow)*64 + kb*16);
        acc[ni] = __builtin_amdgcn_mfma_f32_16x16x32_f16(ah, bh, acc[ni], 0,0,0);
      }
    }
    #pragma unroll
    for(int q=0;q<4;q++){
      int row = i0 + wm*16 + rg*4 + q;
      float fi = (float)row;
      float wgt;
      if(fi < lf)        wgt = 1.f-(lf-fi)/ctx;
      else if(fi <= rrv) wgt = 0.f;
      else if(fi < tlf)  wgt = 1.f-(fi-rrv)/ctx;
      else               wgt = 0.f;
      #pragma unroll
      for(int ni=0;ni<8;ni++){
        int col = d0 + wn*128 + ni*16 + cc;
        PA[((size_t)b*NLQ + row)*ND + col] = wgt*fmaxf(acc[ni][q], 0.f);
      }
    }
  }
}

// T[l][b*256+j] = h1[b,j,:] . v_l
__global__ __launch_bounds__(256) void k_tv(const float* __restrict__ h1,
                                            const float* __restrict__ v,
                                            float* __restrict__ T){
  int row  = blockIdx.x*4 + (threadIdx.x>>6);
  int lane = threadIdx.x & 63;
  const float4* hr = (const float4*)(h1 + (size_t)row*ND);
  float4 h0 = hr[lane], h1v = hr[lane+64];
  float s0,s1,s2,s3,s4;
  #define DOTV(SL, L) { \
    const float4* vr = (const float4*)(v + (L)*ND); \
    float4 v0 = vr[lane], v1 = vr[lane+64]; \
    float dd = h0.x*v0.x+h0.y*v0.y+h0.z*v0.z+h0.w*v0.w \
             + h1v.x*v1.x+h1v.y*v1.y+h1v.z*v1.z+h1v.w*v1.w; \
    SL = wave_sum(dd); }
  DOTV(s0,0) DOTV(s1,1) DOTV(s2,2) DOTV(s3,3) DOTV(s4,4)
  #undef DOTV
  if(lane==0){
    T[0*32768 + row]=s0; T[1*32768 + row]=s1; T[2*32768 + row]=s2;
    T[3*32768 + row]=s3; T[4*32768 + row]=s4;
  }
}

// R16[b*8+k,:] = fp16(h1[b, l0+k, :]) or 0
__global__ __launch_bounds__(256) void k_rows(const float* __restrict__ h1,
                                              const int* __restrict__ left, const int* __restrict__ asp,
                                              ushort_t* __restrict__ R){
  int b = blockIdx.x;
  int nk = asp[b], l0 = left[b];
  const float* src = h1 + (size_t)b*NLQ*ND;
  unsigned int* dst = (unsigned int*)(R + (size_t)b*8*ND);
  #pragma unroll
  for(int u=0; u<8; u++){
    int idx = threadIdx.x + u*256;     // 0..2047 u32
    int k = idx >> 8, c = idx & 255;
    float2 vv = (k<nk) ? ((const float2*)(src + (size_t)(l0+k)*ND))[c] : (float2){0.f,0.f};
    dst[idx] = pk16(vv.x, vv.y);
  }
}

// one block per (layer, batch): 5 aspect-row atts + y16 = fp16(att @ h1).
__global__ __launch_bounds__(256) void k_att5(const float* __restrict__ h1,
    const float* __restrict__ Hasp, const float* __restrict__ T,
    const int* __restrict__ adj, const float* __restrict__ scal,
    const int* __restrict__ left, const int* __restrict__ asp,
    ushort_t* __restrict__ y){
  __shared__ float att[5][260];
  int b  = blockIdx.x & 127;
  int l  = blockIdx.x >> 7;
  int tid = threadIdx.x, lane = tid&63, w = tid>>6;
  int nk = asp[b], l0 = left[b];
  float S0 = scal[2*(l+1)], S1 = scal[2*(l+1)+1];

  for(int k = w; k < 5; k += 4){
    if(k < nk){
      const float2* hrow = (const float2*)(Hasp + (size_t)l*MN + (size_t)(b*8+k)*ND);
      const int* arow = adj + ((size_t)b*NLQ + (l0+k))*NLQ;
      const float* Tl = T + l*32768 + b*256;
      float e[4]; int av[4];
      float m = -3.0e38f;
      #pragma unroll
      for(int q=0;q<4;q++){
        int j = lane + 64*q;
        float2 hp = hrow[j];
        av[q] = arow[j];
        e[q] = fmaxf(S0*hp.x + S1*hp.y + Tl[j], 0.f);
        if(av[q] > 0) m = fmaxf(m, e[q]);
      }
      m = wave_max(m);
      float pp[4]; float s = 0.f;
      #pragma unroll
      for(int q=0;q<4;q++){
        pp[q] = (av[q] > 0) ? __expf(e[q]-m) : 0.f;
        s += pp[q];
      }
      s = wave_sum(s);
      float inv = 1.f/s;
      #pragma unroll
      for(int q=0;q<4;q++) att[k][lane+64*q] = pp[q]*inv;
    } else {
      #pragma unroll
      for(int q=0;q<4;q++) att[k][lane+64*q] = 0.f;
    }
  }
  __syncthreads();

  int d = tid;
  const float* hb = h1 + (size_t)b*NLQ*ND;
  float ax[5] = {0,0,0,0,0}, ay[5] = {0,0,0,0,0};
  for(int jj=0; jj<NLQ; jj++){
    float hx = hb[(size_t)jj*ND + d];
    float hy = hb[(size_t)jj*ND + 256 + d];
    #pragma unroll
    for(int k=0;k<5;k++){
      float a = att[k][jj];
      ax[k] += a*hx;
      ay[k] += a*hy;
    }
  }
  ushort_t* yb = y + (size_t)l*MN + (size_t)b*8*ND;
  #pragma unroll
  for(int k=0;k<5;k++){
    yb[(size_t)k*ND + d]       = __builtin_bit_cast(unsigned short, (_Float16)ax[k]);
    yb[(size_t)k*ND + 256 + d] = __builtin_bit_cast(unsigned short, (_Float16)ay[k]);
  }
  #pragma unroll
  for(int u=0;u<6;u++) yb[5*ND + u*256 + tid] = 0;
}

__global__ __launch_bounds__(256) void k_g(const float* __restrict__ hp,
    const int* __restrict__ asp, float* __restrict__ g){
  int b = blockIdx.x, d = threadIdx.x;
  int nk = asp[b];
  float gx=0.f, gy=0.f;
  for(int l=0;l<5;l++){
    for(int k=0;k<nk;k++){
      const float* r = hp + (size_t)l*MN + (size_t)(b*8+k)*ND;
      gx += fmaxf(r[d], 0.f);
      gy += fmaxf(r[d+256], 0.f);
    }
  }
  g[b*ND + d]       = 0.2f*gx;
  g[b*ND + 256 + d] = 0.2f*gy;
}

__global__ __launch_bounds__(256) void k_dot(const float* __restrict__ x,
    const float* __restrict__ g, float* __restrict__ s){
  int row  = blockIdx.x*4 + (threadIdx.x>>6);
  int b    = row >> 8;
  int lane = threadIdx.x & 63;
  const float4* xr = (const float4*)(x + (size_t)row*ND);
  const float4* gr = (const float4*)(g + (size_t)b*ND);
  float4 x0=xr[lane], x1=xr[lane+64], g0=gr[lane], g1=gr[lane+64];
  float d = x0.x*g0.x + x0.y*g0.y + x0.z*g0.z + x0.w*g0.w
          + x1.x*g1.x + x1.y*g1.y + x1.z*g1.z + x1.w*g1.w;
  d = wave_sum(d);
  if(lane==0) s[row] = d;
}

__global__ __launch_bounds__(256) void k_out(const float* __restrict__ x,
    const float* __restrict__ s, float* __restrict__ out){
  int b  = blockIdx.x >> 2;
  int ch = blockIdx.x & 3;
  int tid = threadIdx.x, lane = tid&63, w = tid>>6;
  __shared__ float red[4];
  __shared__ float alpha[NLQ];
  __shared__ float part[128];
  float sv = s[b*NLQ + tid];
  float m = wave_max(sv);
  if(lane==0) red[w] = m;
  __syncthreads();
  m = fmaxf(fmaxf(red[0],red[1]), fmaxf(red[2],red[3]));
  float p = __expf(sv - m);
  float su = wave_sum(p);
  __syncthreads();
  if(lane==0) red[w] = su;
  __syncthreads();
  su = red[0]+red[1]+red[2]+red[3];
  alpha[tid] = p/su;
  __syncthreads();
  int d = ch*128 + (tid & 127);
  int half = tid >> 7;
  const float* xb = x + (size_t)b*NLQ*ND;
  float acc = 0.f;
  for(int mm = half*128; mm < half*128 + 128; mm++)
    acc += alpha[mm] * xb[(size_t)mm*ND + d];
  if(half) part[tid & 127] = acc;
  __syncthreads();
  if(!half) out[(size_t)b*ND + d] = acc + part[tid & 127];
}

extern "C" void kernel_launch(void* const* d_in, const int* in_sizes, int n_in,
                              void* d_out, int out_size, void* d_ws, size_t ws_size,
                              hipStream_t stream){
  const float* x    = (const float*)d_in[0];
  const float* Wst  = (const float*)d_in[1];
  const float* ast  = (const float*)d_in[2];
  const int*   adj  = (const int*)d_in[3];
  const int*   left = (const int*)d_in[4];
  const int*   asp  = (const int*)d_in[5];
  const int*   tl   = (const int*)d_in[6];
  float* out = (float*)d_out;
  float* ws  = (float*)d_ws;

  const size_t SZ = (size_t)NB*NLQ*ND;
  float* bufA = ws;                     // P (fp16, packed per tile) -> h1
  float* bufB = ws + SZ;                // [0..8.39M): hT plane; [8.39M..16.78M): xp16
  float* ws2  = ws + 2*SZ;
  float* tpart= ws2;                    // 4*32768
  float* T    = tpart + 4*32768;        // 163840
  float* g    = T + 163840;             // 65536
  float* scal = g + 65536;              // 16
  float* v    = scal + 16;              // 2560
  float* sbuf = v + 2560;               // 32768
  ushort_t* w0th = (ushort_t*)(sbuf + 32768);  // DD ushorts (layer-0 Wt fp16)

  ushort_t* hTH  = (ushort_t*)bufB;                  // NB*HTB fp16
  ushort_t* xp16 = (ushort_t*)(bufB + (SZ>>1));      // NB*NLQ*ND fp16 (dead after k_gemm_t)

  float* Hasp = bufB;                   // reuse after k_attn0
  ushort_t* y16 = (ushort_t*)(Hasp + (size_t)5*MN);  // 5*MN fp16
  float* hp   = Hasp + (size_t)10*MN;
  ushort_t* R16 = (ushort_t*)(hp + (size_t)5*MN);    // 1024*ND fp16
  ushort_t* wt15h = (ushort_t*)(hp + (size_t)5*MN + (MN>>1));  // 5*DD ushorts

  k_scal<<<NLAYERS, 256, 0, stream>>>(ast, scal);
  k_wa2<<<5*128, 256, 0, stream>>>(Wst, ast, v);
  k_wcvt<<<64, 256, 0, stream>>>(Wst, w0th);
  k_xposw<<<8192, 256, 0, stream>>>(x, xp16, left, asp, tl);

  // layer 0: pure fp16 GEMM (gload_lds both sides, swizzled); emits plane + P + t-partials
  k_gemm_t<<<(NB*NLQ/128)*(ND/128), 512, 0, stream>>>(xp16, w0th,
      (unsigned int*)hTH, (ushort_t*)bufA, tpart, ast + ND, scal);
  k_attn0<<<NB*8, 256, 0, stream>>>(hTH, adj, tpart, left, asp, tl, bufA);

  // layers 1..5 on aspect rows only
  k_wcvt<<<5*64, 256, 0, stream>>>(Wst + DD, wt15h);
  k_tv<<<NB*NLQ/4, 256, 0, stream>>>(bufA, v, T);
  k_rows<<<NB, 256, 0, stream>>>(bufA, left, asp, R16);
  k_gemm_b<<<5*32, 512, 0, stream>>>(R16, 0L, wt15h, Hasp);
  k_att5<<<5*NB, 256, 0, stream>>>(bufA, Hasp, T, adj, scal, left, asp, y16);
  k_gemm_b<<<5*32, 512, 0, stream>>>(y16, (long)MN, wt15h, hp);
  k_g<<<NB, 256, 0, stream>>>(hp, asp, g);

  // final attention over original x
  k_dot<<<NB*NLQ/4, 256, 0, stream>>>(x, g, sbuf);
  k_out<<<NB*4, 256, 0, stream>>>(x, sbuf, out);
}

// Round 18
// 213.166 us; speedup vs baseline: 1.0556x; 1.0265x over previous
//
#include <hip/hip_runtime.h>

#define NB 128
#define NLQ 256   // sequence length L
#define ND 512    // feature dim D
#define NLAYERS 6
#define DD (ND*ND)
#define MN (1024*ND)
#define HTB 131072   // fp16 elems per batch in hT plane: 512*256

typedef _Float16 f16x8 __attribute__((ext_vector_type(8)));
typedef __fp16 fp16x2 __attribute__((ext_vector_type(2)));
typedef _Float16 f16x4v __attribute__((ext_vector_type(4)));
typedef float f32x4 __attribute__((ext_vector_type(4)));
typedef unsigned int u32x2 __attribute__((ext_vector_type(2)));
typedef unsigned int u32x4 __attribute__((ext_vector_type(4)));
typedef unsigned short ushort_t;

#define GLOAD16(gp, lp) __builtin_amdgcn_global_load_lds( \
    (const __attribute__((address_space(1))) void*)(gp), \
    (__attribute__((address_space(3))) void*)(lp), 16, 0, 0)

__device__ __forceinline__ float wave_max(float v){
  #pragma unroll
  for(int off=32; off; off>>=1) v = fmaxf(v, __shfl_xor(v, off));
  return v;
}
__device__ __forceinline__ float wave_sum(float v){
  #pragma unroll
  for(int off=32; off; off>>=1) v += __shfl_xor(v, off);
  return v;
}
__device__ __forceinline__ unsigned int pk16(float a, float b){
  fp16x2 h = __builtin_amdgcn_cvt_pkrtz(a, b);
  return __builtin_bit_cast(unsigned int, h);
}
__device__ __forceinline__ float f16u(ushort_t u){
  return (float)__builtin_bit_cast(_Float16, u);
}

__global__ __launch_bounds__(256) void k_scal(const float* __restrict__ a_stack,
                                              float* __restrict__ scal){
  int layer = blockIdx.x;
  const float* a = a_stack + (size_t)layer*2*ND;
  int t = threadIdx.x;
  float v0 = a[t];
  float v1 = a[256 + t];
  v0 = wave_sum(v0); v1 = wave_sum(v1);
  __shared__ float s0[4], s1[4];
  int wave = t>>6, lane = t&63;
  if(lane==0){ s0[wave]=v0; s1[wave]=v1; }
  __syncthreads();
  if(t==0){
    scal[layer*2+0] = s0[0]+s0[1]+s0[2]+s0[3];
    scal[layer*2+1] = s1[0]+s1[1]+s1[2]+s1[3];
  }
}

// v_l[i] = dot(W_{l+1}[i,:], a2_{l+1})
__global__ __launch_bounds__(256) void k_wa2(const float* __restrict__ Wst,
                                             const float* __restrict__ ast,
                                             float* __restrict__ v){
  int l  = blockIdx.x >> 7;
  int rg = blockIdx.x & 127;
  int i  = rg*4 + (threadIdx.x>>6);
  int lane = threadIdx.x & 63;
  const float4* wr = (const float4*)(Wst + (size_t)(l+1)*DD + (size_t)i*ND);
  const float4* ar = (const float4*)(ast + (size_t)(l+1)*2*ND + ND);
  float4 w0=wr[lane], w1=wr[lane+64], a0=ar[lane], a1=ar[lane+64];
  float d = w0.x*a0.x + w0.y*a0.y + w0.z*a0.z + w0.w*a0.w
          + w1.x*a1.x + w1.y*a1.y + w1.z*a1.z + w1.w*a1.w;
  d = wave_sum(d);
  if(lane==0) v[l*ND + i] = d;
}

// transpose + convert W layers to fp16 plane Wt[n][k]. One 64x64 tile per block.
__global__ __launch_bounds__(256) void k_wcvt(const float* __restrict__ Wsrc,
                                              ushort_t* __restrict__ Ho){
  __shared__ float CT[64][65];
  int bid = blockIdx.x;
  int l  = bid >> 6;
  int kt = (bid >> 3) & 7, nt = bid & 7;
  const float* Wl = Wsrc + (size_t)l*DD;
  int t = threadIdx.x;
  int r = t >> 2, c4 = (t&3)*16;
  #pragma unroll
  for(int u=0;u<4;u++){
    float4 vv = *(const float4*)(Wl + (size_t)(kt*64+r)*ND + nt*64 + c4 + u*4);
    CT[r][c4+u*4+0]=vv.x; CT[r][c4+u*4+1]=vv.y;
    CT[r][c4+u*4+2]=vv.z; CT[r][c4+u*4+3]=vv.w;
  }
  __syncthreads();
  int n = t >> 2, kc = t & 3;
  unsigned int o[8];
  #pragma unroll
  for(int j=0;j<8;j++)
    o[j] = pk16(CT[kc*16 + 2*j][n], CT[kc*16 + 2*j + 1][n]);
  ushort_t* dh = Ho + (size_t)l*DD + (size_t)(nt*64+n)*ND + kt*64 + kc*16;
  *(u32x4*)(dh)     = (u32x4){o[0],o[1],o[2],o[3]};
  *(u32x4*)(dh + 8) = (u32x4){o[4],o[5],o[6],o[7]};
}

// x16 = fp16(x), no posw (posw folded into gemm_t epilogue)
__global__ __launch_bounds__(256) void k_xcvt(const float* __restrict__ x,
                                              ushort_t* __restrict__ xp){
  int c = blockIdx.x*256 + threadIdx.x;
  const float4* xr = (const float4*)x;
  float4 v0 = xr[(size_t)c*2], v1 = xr[(size_t)c*2+1];
  u32x4 o = (u32x4){ pk16(v0.x, v0.y), pk16(v0.z, v0.w),
                     pk16(v1.x, v1.y), pk16(v1.z, v1.w) };
  *(u32x4*)(xp + (size_t)c*8) = o;
}

// ---- fp16 MFMA GEMM tile, BK=64, global_load_lds both operands, LDS dbuf,
// XOR-swizzled. 512 threads (8 waves 2x4), wave tile 64x32.
// MODE=0: C row-major [M][512].
// MODE=1: posw row-scale applied to acc; outputs transposed fp16 plane hP[b][d][i],
//         Pscore fp16 (compact), t-partials tp4.
#define BKB 128
template<int MODE>
__device__ __forceinline__ void gemm_tile(const ushort_t* __restrict__ A16,
                                          const ushort_t* __restrict__ Wth,
                                          float* __restrict__ C,
                                          unsigned int* __restrict__ hP,
                                          ushort_t* __restrict__ Pbuf,
                                          float* __restrict__ tp4,
                                          const float* __restrict__ a2,
                                          const float* __restrict__ scal,
                                          const int* __restrict__ left,
                                          const int* __restrict__ asp,
                                          const int* __restrict__ tl,
                                          int mtile, int ntile, unsigned char* lds){
  int t = threadIdx.x;                      // 0..511
  int m0 = mtile*128, n0 = ntile*128;
  int lane = t & 63, wid = t >> 6;
  int wr = wid >> 2, wcq = wid & 3;
  int lrow = lane & 15, kb = lane >> 4;

  f32x4 acc[4][2];
  #pragma unroll
  for(int mi=0;mi<4;mi++)
    #pragma unroll
    for(int ni=0;ni<2;ni++)
      acc[mi][ni] = (f32x4){0.f,0.f,0.f,0.f};

  int s_row = t >> 3;                 // 0..63
  int s_sl  = (t & 7) ^ (s_row & 7);  // pre-swizzled source slot
  int dstoff = wid*1024;              // wave-uniform; hw adds lane*16

  const ushort_t* Asrc0 = A16 + (size_t)(m0 + s_row)*ND + s_sl*8;
  const ushort_t* Asrc1 = A16 + (size_t)(m0 + 64 + s_row)*ND + s_sl*8;
  const ushort_t* Bsrc0 = Wth + (size_t)(n0 + s_row)*ND + s_sl*8;
  const ushort_t* Bsrc1 = Wth + (size_t)(n0 + 64 + s_row)*ND + s_sl*8;

  GLOAD16(Asrc0, lds + dstoff);
  GLOAD16(Asrc1, lds + 8192 + dstoff);
  GLOAD16(Bsrc0, lds + 16384 + dstoff);
  GLOAD16(Bsrc1, lds + 24576 + dstoff);
  __syncthreads();

  int cur = 0;
  for(int it=0; it<8; ++it){
    if(it < 7){
      int kn = (it+1)*64;
      unsigned char* dst = lds + ((cur^1)<<15);
      GLOAD16(Asrc0 + kn, dst + dstoff);
      GLOAD16(Asrc1 + kn, dst + 8192 + dstoff);
      GLOAD16(Bsrc0 + kn, dst + 16384 + dstoff);
      GLOAD16(Bsrc1 + kn, dst + 24576 + dstoff);
    }
    unsigned char* Ab = lds + (cur<<15);
    unsigned char* Bb = Ab + 16384;
    #pragma unroll
    for(int ks=0; ks<2; ks++){
      f16x8 ah[4], bh[2];
      #pragma unroll
      for(int mi=0;mi<4;mi++){
        int ar = wr*64 + mi*16 + lrow;
        int sl = (ks*4 + kb) ^ (ar & 7);
        ah[mi] = *(const f16x8*)(Ab + ar*BKB + sl*16);
      }
      #pragma unroll
      for(int ni=0;ni<2;ni++){
        int br = wcq*32 + ni*16 + lrow;
        int sl = (ks*4 + kb) ^ (br & 7);
        bh[ni] = *(const f16x8*)(Bb + br*BKB + sl*16);
      }
      #pragma unroll
      for(int mi=0;mi<4;mi++)
        #pragma unroll
        for(int ni=0;ni<2;ni++)
          acc[mi][ni] = __builtin_amdgcn_mfma_f32_16x16x32_f16(ah[mi], bh[ni], acc[mi][ni], 0,0,0);
    }
    __syncthreads();
    cur ^= 1;
  }

  int rg = lane >> 4;
  int cc = lane & 15;
  if(MODE == 0){
    #pragma unroll
    for(int mi=0;mi<4;mi++)
      #pragma unroll
      for(int ni=0;ni<2;ni++){
        int col = n0 + wcq*32 + ni*16 + cc;
        #pragma unroll
        for(int q=0;q<4;q++){
          int row = m0 + wr*64 + mi*16 + rg*4 + q;
          C[(size_t)row*ND + col] = acc[mi][ni][q];
        }
      }
  } else {
    float S0 = scal[0], S1 = scal[1];
    float* CT = (float*)lds;
    int b = m0 >> 8;
    int ibase = m0 & 255;
    // posw row-scale (h0 = diag(w) * (x @ W0))
    {
      float lf=(float)left[b], aspf=(float)asp[b], tlf=(float)tl[b];
      float rrow=lf+aspf-1.f, inv_ctx=1.f/(tlf-aspf);
      #pragma unroll
      for(int mi=0;mi<4;mi++)
        #pragma unroll
        for(int q=0;q<4;q++){
          float jf = (float)(ibase + wr*64 + mi*16 + rg*4 + q);
          float w;
          if(jf < lf)         w = 1.f-(lf-jf)*inv_ctx;
          else if(jf <= rrow) w = 0.f;
          else if(jf < tlf)   w = 1.f-(jf-rrow)*inv_ctx;
          else                w = 0.f;
          acc[mi][0][q] *= w;
          acc[mi][1][q] *= w;
        }
    }
    int tr   = t >> 2;
    int tch  = t & 3;
    float tpsum = 0.f;
    #pragma unroll
    for(int p=0;p<2;p++){
      if((wcq>>1) == p){
        #pragma unroll
        for(int mi=0;mi<4;mi++)
          #pragma unroll
          for(int ni=0;ni<2;ni++)
            #pragma unroll
            for(int q=0;q<4;q++)
              CT[((wcq&1)*32 + ni*16 + cc)*130 + wr*64 + mi*16 + rg*4 + q] = acc[mi][ni][q];
      }
      __syncthreads();
      // transposed fp16 plane [b][d][i]
      int lcol = t >> 6;
      int lrow2 = (t & 63)*2;
      #pragma unroll
      for(int u=0;u<8;u++){
        int c = lcol + u*8;
        float2 v2 = *(float2*)&CT[c*130 + lrow2];
        size_t uidx = ((size_t)b*HTB + (size_t)(n0 + p*64 + c)*256 + ibase + lrow2) >> 1;
        hP[uidx] = pk16(v2.x, v2.y);
      }
      // Pscore fp16, compact layout: b*65536 + itile*8192 + (i&31)*256 + j
      {
        int cpr = t & 31;
        int rq  = t >> 5;
        #pragma unroll
        for(int rr2=0; rr2<8; rr2++){
          int row = rq*8 + rr2;
          float pval = S0*CT[(2*cpr)*130 + row] + S1*CT[(2*cpr+1)*130 + row];
          int ig = ibase + row;
          _Float16 ph = (_Float16)pval;
          size_t addr = (size_t)b*65536 + (size_t)(ig>>5)*8192
                      + (size_t)(ig&31)*256 + (n0>>1) + p*32 + cpr;
          Pbuf[addr] = __builtin_bit_cast(unsigned short, ph);
        }
      }
      // t-partial over this 64-d slab
      #pragma unroll
      for(int cc2=0; cc2<16; cc2++){
        int c = tch*16 + cc2;
        tpsum = fmaf(CT[c*130 + tr], a2[n0 + p*64 + c], tpsum);
      }
      __syncthreads();
    }
    tpsum += __shfl_xor(tpsum, 1);
    tpsum += __shfl_xor(tpsum, 2);
    if(tch == 0) tp4[(n0>>7)*32768 + m0 + tr] = tpsum;
  }
}

__global__ __launch_bounds__(512) void k_gemm_t(const ushort_t* __restrict__ A16,
                                                const ushort_t* __restrict__ Wth,
                                                unsigned int* __restrict__ hP,
                                                ushort_t* __restrict__ Pbuf,
                                                float* __restrict__ tp4,
                                                const float* __restrict__ a2,
                                                const float* __restrict__ scal,
                                                const int* __restrict__ left,
                                                const int* __restrict__ asp,
                                                const int* __restrict__ tl){
  __shared__ unsigned char lds[65536];
  int bid = blockIdx.x;
  int ntile = (bid >> 3) & 3;
  int mtile = (bid & 7) | ((bid >> 5) << 3);
  gemm_tile<1>(A16, Wth, nullptr, hP, Pbuf, tp4, a2, scal, left, asp, tl,
               mtile, ntile, lds);
}

__global__ __launch_bounds__(512) void k_gemm_b(const ushort_t* __restrict__ Abase, long aStride,
                                                const ushort_t* __restrict__ Wth,
                                                float* __restrict__ Cbase){
  __shared__ unsigned char lds[65536];
  int l  = blockIdx.x >> 5;
  int tb = blockIdx.x & 31;
  gemm_tile<0>(Abase + (size_t)l*aStride, Wth + (size_t)l*DD,
               Cbase + (size_t)l*MN, nullptr, nullptr, nullptr,
               nullptr, nullptr, nullptr, nullptr, nullptr, tb>>2, tb&3, lds);
}

// layer-0 attention: coalesced fp16-P softmax + MFMA aggregation; h1 out fp16.
__global__ __launch_bounds__(256) void k_attn0(
    const ushort_t* __restrict__ hTH,
    const ushort_t* __restrict__ Pbuf,
    const int* __restrict__ adj,
    const float* __restrict__ tpart,
    const int* __restrict__ left, const int* __restrict__ asp, const int* __restrict__ tl,
    ushort_t* __restrict__ h16){
  __shared__ unsigned char attH[32*512];   // fp16 att [32 i][256 j], XOR-swizzled
  __shared__ unsigned char BsH[16384];     // staged fp16 plane [256 d][32 j]

  int bid = blockIdx.x;
  int b  = bid & 127;
  int ic = bid >> 7;
  int i0 = ic*32;
  int tid = threadIdx.x;
  int lane = tid & 63, w = tid >> 6;
  const ushort_t* HH = hTH + (size_t)b*HTB;
  const ushort_t* Pt = Pbuf + (size_t)b*65536 + (size_t)ic*8192;

  // ---- phase 1: softmax, lanes = j ----
  float t0v=0.f, t1v=0.f, t2v=0.f, t3v=0.f;
  #pragma unroll
  for(int nt=0; nt<4; nt++){
    float4 tv = ((const float4*)(tpart + nt*32768 + b*256))[lane];
    t0v += tv.x; t1v += tv.y; t2v += tv.z; t3v += tv.w;
  }

  for(int rr=0; rr<8; rr++){
    int il = w*8 + rr;
    int i  = i0 + il;
    f16x4v pv = *(const f16x4v*)(Pt + il*256 + lane*4);
    int4 av = ((const int4*)(adj + ((size_t)b*NLQ + i)*NLQ))[lane];
    float e0 = fmaxf((float)pv[0] + t0v, 0.f);
    float e1 = fmaxf((float)pv[1] + t1v, 0.f);
    float e2 = fmaxf((float)pv[2] + t2v, 0.f);
    float e3 = fmaxf((float)pv[3] + t3v, 0.f);
    float m = -3.0e38f;
    if(av.x>0) m = e0;
    if(av.y>0) m = fmaxf(m, e1);
    if(av.z>0) m = fmaxf(m, e2);
    if(av.w>0) m = fmaxf(m, e3);
    m = wave_max(m);
    float p0 = (av.x>0) ? __expf(e0-m) : 0.f;
    float p1 = (av.y>0) ? __expf(e1-m) : 0.f;
    float p2 = (av.z>0) ? __expf(e2-m) : 0.f;
    float p3 = (av.w>0) ? __expf(e3-m) : 0.f;
    float s = wave_sum(p0+p1+p2+p3);
    float inv = 1.f/s;
    unsigned int w0 = pk16(p0*inv, p1*inv);
    unsigned int w1 = pk16(p2*inv, p3*inv);
    int off = il*512 + ((lane*8) ^ ((il&7)<<4));
    *(u32x2*)(attH + off) = (u32x2){w0,w1};
  }

  // ---- phase 2: O[i][d] = att @ h via MFMA ----
  int wm = w >> 1, wn = w & 1;
  int lrow = lane & 15, kb = lane >> 4;
  int rg = lane >> 4, cc = lane & 15;
  float lf=(float)left[b], aspf=(float)asp[b], tlf=(float)tl[b];
  float rrv=lf+aspf-1.f, ctx=tlf-aspf;
  int arow = wm*16 + lrow;
  int aswz = (arow&7)<<4;

  for(int dp=0; dp<2; dp++){
    int d0 = dp*256;
    f32x4 acc[8];
    #pragma unroll
    for(int ni=0;ni<8;ni++) acc[ni] = (f32x4){0.f,0.f,0.f,0.f};
    for(int ks=0; ks<8; ks++){
      int j0 = ks*32;
      __syncthreads();
      #pragma unroll
      for(int u=0;u<4;u++){
        int chunk = (u*4 + w)*64 + lane;
        int row = chunk >> 2, sl = chunk & 3;
        GLOAD16(HH + (size_t)(d0+row)*256 + j0 + sl*8, BsH + (u*4+w)*1024);
      }
      __syncthreads();
      int aoff = arow*512 + ((j0*2 + kb*16) ^ aswz);
      f16x8 ah = *(const f16x8*)(attH + aoff);
      #pragma unroll
      for(int ni=0; ni<8; ni++){
        f16x8 bh = *(const f16x8*)(BsH + (wn*128 + ni*16 + lrow)*64 + kb*16);
        acc[ni] = __builtin_amdgcn_mfma_f32_16x16x32_f16(ah, bh, acc[ni], 0,0,0);
      }
    }
    #pragma unroll
    for(int q=0;q<4;q++){
      int row = i0 + wm*16 + rg*4 + q;
      float fi = (float)row;
      float wgt;
      if(fi < lf)        wgt = 1.f-(lf-fi)/ctx;
      else if(fi <= rrv) wgt = 0.f;
      else if(fi < tlf)  wgt = 1.f-(fi-rrv)/ctx;
      else               wgt = 0.f;
      #pragma unroll
      for(int ni=0;ni<8;ni++){
        int col = d0 + wn*128 + ni*16 + cc;
        float ov = wgt*fmaxf(acc[ni][q], 0.f);
        h16[((size_t)b*NLQ + row)*ND + col] =
            __builtin_bit_cast(unsigned short, (_Float16)ov);
      }
    }
  }
}

// T[l][b*256+j] = h1[b,j,:] . v_l   (h1 fp16)
__global__ __launch_bounds__(256) void k_tv(const ushort_t* __restrict__ h16,
                                            const float* __restrict__ v,
                                            float* __restrict__ T){
  int row  = blockIdx.x*4 + (threadIdx.x>>6);
  int lane = threadIdx.x & 63;
  f16x8 hv = *(const f16x8*)(h16 + (size_t)row*ND + lane*8);
  float hf[8];
  #pragma unroll
  for(int i=0;i<8;i++) hf[i] = (float)hv[i];
  float s0,s1,s2,s3,s4;
  #define DOTV(SL, L) { \
    const float4* vr = (const float4*)(v + (L)*ND); \
    float4 v0 = vr[lane*2], v1 = vr[lane*2+1]; \
    float dd = hf[0]*v0.x+hf[1]*v0.y+hf[2]*v0.z+hf[3]*v0.w \
             + hf[4]*v1.x+hf[5]*v1.y+hf[6]*v1.z+hf[7]*v1.w; \
    SL = wave_sum(dd); }
  DOTV(s0,0) DOTV(s1,1) DOTV(s2,2) DOTV(s3,3) DOTV(s4,4)
  #undef DOTV
  if(lane==0){
    T[0*32768 + row]=s0; T[1*32768 + row]=s1; T[2*32768 + row]=s2;
    T[3*32768 + row]=s3; T[4*32768 + row]=s4;
  }
}

// R16[b*8+k,:] = h16[b, l0+k, :] or 0 (straight fp16 copy)
__global__ __launch_bounds__(256) void k_rows(const ushort_t* __restrict__ h16,
                                              const int* __restrict__ left, const int* __restrict__ asp,
                                              ushort_t* __restrict__ R){
  int b = blockIdx.x;
  int nk = asp[b], l0 = left[b];
  const unsigned int* src = (const unsigned int*)(h16 + (size_t)b*NLQ*ND);
  unsigned int* dst = (unsigned int*)(R + (size_t)b*8*ND);
  #pragma unroll
  for(int u=0; u<8; u++){
    int idx = threadIdx.x + u*256;     // 0..2047 u32
    int k = idx >> 8, c = idx & 255;
    dst[idx] = (k<nk) ? src[(size_t)(l0+k)*256 + c] : 0u;
  }
}

// one block per (layer, batch): 5 aspect-row atts + y16 = fp16(att @ h1).
__global__ __launch_bounds__(256) void k_att5(const ushort_t* __restrict__ h16,
    const float* __restrict__ Hasp, const float* __restrict__ T,
    const int* __restrict__ adj, const float* __restrict__ scal,
    const int* __restrict__ left, const int* __restrict__ asp,
    ushort_t* __restrict__ y){
  __shared__ float att[5][260];
  int b  = blockIdx.x & 127;
  int l  = blockIdx.x >> 7;
  int tid = threadIdx.x, lane = tid&63, w = tid>>6;
  int nk = asp[b], l0 = left[b];
  float S0 = scal[2*(l+1)], S1 = scal[2*(l+1)+1];

  for(int k = w; k < 5; k += 4){
    if(k < nk){
      const float2* hrow = (const float2*)(Hasp + (size_t)l*MN + (size_t)(b*8+k)*ND);
      const int* arow = adj + ((size_t)b*NLQ + (l0+k))*NLQ;
      const float* Tl = T + l*32768 + b*256;
      float e[4]; int av[4];
      float m = -3.0e38f;
      #pragma unroll
      for(int q=0;q<4;q++){
        int j = lane + 64*q;
        float2 hp = hrow[j];
        av[q] = arow[j];
        e[q] = fmaxf(S0*hp.x + S1*hp.y + Tl[j], 0.f);
        if(av[q] > 0) m = fmaxf(m, e[q]);
      }
      m = wave_max(m);
      float pp[4]; float s = 0.f;
      #pragma unroll
      for(int q=0;q<4;q++){
        pp[q] = (av[q] > 0) ? __expf(e[q]-m) : 0.f;
        s += pp[q];
      }
      s = wave_sum(s);
      float inv = 1.f/s;
      #pragma unroll
      for(int q=0;q<4;q++) att[k][lane+64*q] = pp[q]*inv;
    } else {
      #pragma unroll
      for(int q=0;q<4;q++) att[k][lane+64*q] = 0.f;
    }
  }
  __syncthreads();

  int d = tid;
  const ushort_t* hb = h16 + (size_t)b*NLQ*ND;
  float ax[5] = {0,0,0,0,0}, ay[5] = {0,0,0,0,0};
  for(int jj=0; jj<NLQ; jj++){
    float hx = f16u(hb[(size_t)jj*ND + d]);
    float hy = f16u(hb[(size_t)jj*ND + 256 + d]);
    #pragma unroll
    for(int k=0;k<5;k++){
      float a = att[k][jj];
      ax[k] += a*hx;
      ay[k] += a*hy;
    }
  }
  ushort_t* yb = y + (size_t)l*MN + (size_t)b*8*ND;
  #pragma unroll
  for(int k=0;k<5;k++){
    yb[(size_t)k*ND + d]       = __builtin_bit_cast(unsigned short, (_Float16)ax[k]);
    yb[(size_t)k*ND + 256 + d] = __builtin_bit_cast(unsigned short, (_Float16)ay[k]);
  }
  #pragma unroll
  for(int u=0;u<6;u++) yb[5*ND + u*256 + tid] = 0;
}

__global__ __launch_bounds__(256) void k_g(const float* __restrict__ hp,
    const int* __restrict__ asp, float* __restrict__ g){
  int b = blockIdx.x, d = threadIdx.x;
  int nk = asp[b];
  float gx=0.f, gy=0.f;
  for(int l=0;l<5;l++){
    for(int k=0;k<nk;k++){
      const float* r = hp + (size_t)l*MN + (size_t)(b*8+k)*ND;
      gx += fmaxf(r[d], 0.f);
      gy += fmaxf(r[d+256], 0.f);
    }
  }
  g[b*ND + d]       = 0.2f*gx;
  g[b*ND + 256 + d] = 0.2f*gy;
}

// s[b,m] = g[b,:] . x16[b,m,:]
__global__ __launch_bounds__(256) void k_dot(const ushort_t* __restrict__ x16,
    const float* __restrict__ g, float* __restrict__ s){
  int row  = blockIdx.x*4 + (threadIdx.x>>6);
  int b    = row >> 8;
  int lane = threadIdx.x & 63;
  f16x8 xv = *(const f16x8*)(x16 + (size_t)row*ND + lane*8);
  const float4* gr = (const float4*)(g + (size_t)b*ND);
  float4 g0 = gr[lane*2], g1 = gr[lane*2+1];
  float d = (float)xv[0]*g0.x + (float)xv[1]*g0.y + (float)xv[2]*g0.z + (float)xv[3]*g0.w
          + (float)xv[4]*g1.x + (float)xv[5]*g1.y + (float)xv[6]*g1.z + (float)xv[7]*g1.w;
  d = wave_sum(d);
  if(lane==0) s[row] = d;
}

__global__ __launch_bounds__(256) void k_out(const ushort_t* __restrict__ x16,
    const float* __restrict__ s, float* __restrict__ out){
  int b  = blockIdx.x >> 2;
  int ch = blockIdx.x & 3;
  int tid = threadIdx.x, lane = tid&63, w = tid>>6;
  __shared__ float red[4];
  __shared__ float alpha[NLQ];
  __shared__ float part[128];
  float sv = s[b*NLQ + tid];
  float m = wave_max(sv);
  if(lane==0) red[w] = m;
  __syncthreads();
  m = fmaxf(fmaxf(red[0],red[1]), fmaxf(red[2],red[3]));
  float p = __expf(sv - m);
  float su = wave_sum(p);
  __syncthreads();
  if(lane==0) red[w] = su;
  __syncthreads();
  su = red[0]+red[1]+red[2]+red[3];
  alpha[tid] = p/su;
  __syncthreads();
  int d = ch*128 + (tid & 127);
  int half = tid >> 7;
  const ushort_t* xb = x16 + (size_t)b*NLQ*ND;
  float acc = 0.f;
  for(int mm = half*128; mm < half*128 + 128; mm++)
    acc += alpha[mm] * f16u(xb[(size_t)mm*ND + d]);
  if(half) part[tid & 127] = acc;
  __syncthreads();
  if(!half) out[(size_t)b*ND + d] = acc + part[tid & 127];
}

extern "C" void kernel_launch(void* const* d_in, const int* in_sizes, int n_in,
                              void* d_out, int out_size, void* d_ws, size_t ws_size,
                              hipStream_t stream){
  const float* x    = (const float*)d_in[0];
  const float* Wst  = (const float*)d_in[1];
  const float* ast  = (const float*)d_in[2];
  const int*   adj  = (const int*)d_in[3];
  const int*   left = (const int*)d_in[4];
  const int*   asp  = (const int*)d_in[5];
  const int*   tl   = (const int*)d_in[6];
  float* out = (float*)d_out;
  float* ws  = (float*)d_ws;

  const size_t SZ = (size_t)NB*NLQ*ND;   // 16.78M floats
  float* bufA = ws;                      // P (compact fp16) + h16
  float* bufB = ws + SZ;                 // hT plane / Hasp...; x16 in upper half
  float* ws2  = ws + 2*SZ;
  float* tpart= ws2;                     // 4*32768
  float* T    = tpart + 4*32768;         // 163840
  float* g    = T + 163840;              // 65536
  float* scal = g + 65536;               // 16
  float* v    = scal + 16;               // 2560
  float* sbuf = v + 2560;                // 32768
  ushort_t* w0th = (ushort_t*)(sbuf + 32768);  // DD ushorts

  // bufA: P [0 .. 8.39M ushorts), h16 [8.39M .. 25.2M ushorts)
  ushort_t* Pbuf = (ushort_t*)bufA;                  // 128*65536 = 8.39M ushorts
  ushort_t* h16  = Pbuf + (size_t)NB*65536;          // NB*NLQ*ND fp16

  // bufB: hT plane [0 .. 16.78M ushorts) then Hasp-group; x16 at float ofs 8.39M
  ushort_t* hTH  = (ushort_t*)bufB;
  ushort_t* x16  = (ushort_t*)(bufB + (SZ>>1));      // persists whole run

  float* Hasp = bufB;                                // [0, 5MN) floats
  ushort_t* y16 = (ushort_t*)(Hasp + (size_t)5*MN);  // 5MN ushorts
  float* hp   = (float*)(y16 + (size_t)5*MN);        // hmm: keep float-aligned below
  // re-derive cleanly in float units:
  {
    // Hasp: [0, 5MN)
    // y16:  [5MN, 5MN + 5MN/2)
    // hp:   [5MN + 5MN/2, +5MN)
  }
  float* hpF  = bufB + (size_t)5*MN + (size_t)5*MN/2;          // 5MN floats
  ushort_t* R16 = (ushort_t*)(hpF + (size_t)5*MN);             // MN ushorts
  ushort_t* wt15h = (ushort_t*)((float*)R16 + (size_t)MN/2);   // 5*DD ushorts

  k_scal<<<NLAYERS, 256, 0, stream>>>(ast, scal);
  k_wa2<<<5*128, 256, 0, stream>>>(Wst, ast, v);
  k_wcvt<<<64, 256, 0, stream>>>(Wst, w0th);
  k_xcvt<<<8192, 256, 0, stream>>>(x, x16);

  // layer 0: fp16 GEMM (gload_lds both sides, swizzled); posw in epilogue;
  // emits plane + compact P + t-partials
  k_gemm_t<<<(NB*NLQ/128)*(ND/128), 512, 0, stream>>>(x16, w0th,
      (unsigned int*)hTH, Pbuf, tpart, ast + ND, scal, left, asp, tl);
  k_attn0<<<NB*8, 256, 0, stream>>>(hTH, Pbuf, adj, tpart, left, asp, tl, h16);

  // layers 1..5 on aspect rows only
  k_wcvt<<<5*64, 256, 0, stream>>>(Wst + DD, wt15h);
  k_tv<<<NB*NLQ/4, 256, 0, stream>>>(h16, v, T);
  k_rows<<<NB, 256, 0, stream>>>(h16, left, asp, R16);
  k_gemm_b<<<5*32, 512, 0, stream>>>(R16, 0L, wt15h, Hasp);
  k_att5<<<5*NB, 256, 0, stream>>>(h16, Hasp, T, adj, scal, left, asp, y16);
  k_gemm_b<<<5*32, 512, 0, stream>>>(y16, (long)MN, wt15h, hpF);
  k_g<<<NB, 256, 0, stream>>>(hpF, asp, g);

  // final attention over original x (fp16 copy)
  k_dot<<<NB*NLQ/4, 256, 0, stream>>>(x16, g, sbuf);
  k_out<<<NB*4, 256, 0, stream>>>(x16, sbuf, out);
}

// Round 20
// 210.770 us; speedup vs baseline: 1.0676x; 1.0114x over previous
//
#include <hip/hip_runtime.h>

#define NB 128
#define NLQ 256   // sequence length L
#define ND 512    // feature dim D
#define NLAYERS 6
#define DD (ND*ND)
#define MN (1024*ND)
#define HTB 131072   // fp16 elems per batch in hT plane: 512*256

typedef _Float16 f16x8 __attribute__((ext_vector_type(8)));
typedef __fp16 fp16x2 __attribute__((ext_vector_type(2)));
typedef _Float16 f16x4v __attribute__((ext_vector_type(4)));
typedef float f32x4 __attribute__((ext_vector_type(4)));
typedef unsigned int u32x2 __attribute__((ext_vector_type(2)));
typedef unsigned int u32x4 __attribute__((ext_vector_type(4)));
typedef unsigned short ushort_t;

#define GLOAD16(gp, lp) __builtin_amdgcn_global_load_lds( \
    (const __attribute__((address_space(1))) void*)(gp), \
    (__attribute__((address_space(3))) void*)(lp), 16, 0, 0)

__device__ __forceinline__ float wave_max(float v){
  #pragma unroll
  for(int off=32; off; off>>=1) v = fmaxf(v, __shfl_xor(v, off));
  return v;
}
__device__ __forceinline__ float wave_sum(float v){
  #pragma unroll
  for(int off=32; off; off>>=1) v += __shfl_xor(v, off);
  return v;
}
__device__ __forceinline__ unsigned int pk16(float a, float b){
  fp16x2 h = __builtin_amdgcn_cvt_pkrtz(a, b);
  return __builtin_bit_cast(unsigned int, h);
}
__device__ __forceinline__ float f16u(ushort_t u){
  return (float)__builtin_bit_cast(_Float16, u);
}

// ---- merged prologue: scal | wa2 | wcvt(l0) | wcvt(l1..5) | xcvt ----
__global__ __launch_bounds__(256) void k_prep(const float* __restrict__ Wst,
                                              const float* __restrict__ ast,
                                              const float* __restrict__ x,
                                              float* __restrict__ scal,
                                              float* __restrict__ v,
                                              ushort_t* __restrict__ w0th,
                                              ushort_t* __restrict__ wt15h,
                                              ushort_t* __restrict__ xp){
  __shared__ float CT[64][65];
  int bid = blockIdx.x;
  int t = threadIdx.x;
  if(bid < 6){
    int layer = bid;
    const float* a = ast + (size_t)layer*2*ND;
    float v0 = a[t];
    float v1 = a[256 + t];
    v0 = wave_sum(v0); v1 = wave_sum(v1);
    float* s0 = &CT[0][0];
    float* s1 = &CT[1][0];
    int wave = t>>6, lane = t&63;
    if(lane==0){ s0[wave]=v0; s1[wave]=v1; }
    __syncthreads();
    if(t==0){
      scal[layer*2+0] = s0[0]+s0[1]+s0[2]+s0[3];
      scal[layer*2+1] = s1[0]+s1[1]+s1[2]+s1[3];
    }
    return;
  }
  if(bid < 646){
    int b2 = bid - 6;
    int l  = b2 >> 7;
    int rg = b2 & 127;
    int i  = rg*4 + (t>>6);
    int lane = t & 63;
    const float4* wr = (const float4*)(Wst + (size_t)(l+1)*DD + (size_t)i*ND);
    const float4* ar = (const float4*)(ast + (size_t)(l+1)*2*ND + ND);
    float4 w0=wr[lane], w1=wr[lane+64], a0=ar[lane], a1=ar[lane+64];
    float d = w0.x*a0.x + w0.y*a0.y + w0.z*a0.z + w0.w*a0.w
            + w1.x*a1.x + w1.y*a1.y + w1.z*a1.z + w1.w*a1.w;
    d = wave_sum(d);
    if(lane==0) v[l*ND + i] = d;
    return;
  }
  if(bid < 1030){
    const float* Wsrc; ushort_t* Ho; int b3;
    if(bid < 710){ Wsrc = Wst;      Ho = w0th;  b3 = bid - 646; }
    else         { Wsrc = Wst + DD; Ho = wt15h; b3 = bid - 710; }
    int l  = b3 >> 6;
    int kt = (b3 >> 3) & 7, nt = b3 & 7;
    const float* Wl = Wsrc + (size_t)l*DD;
    int r = t >> 2, c4 = (t&3)*16;
    #pragma unroll
    for(int u=0;u<4;u++){
      float4 vv = *(const float4*)(Wl + (size_t)(kt*64+r)*ND + nt*64 + c4 + u*4);
      CT[r][c4+u*4+0]=vv.x; CT[r][c4+u*4+1]=vv.y;
      CT[r][c4+u*4+2]=vv.z; CT[r][c4+u*4+3]=vv.w;
    }
    __syncthreads();
    int n = t >> 2, kc = t & 3;
    unsigned int o[8];
    #pragma unroll
    for(int j=0;j<8;j++)
      o[j] = pk16(CT[kc*16 + 2*j][n], CT[kc*16 + 2*j + 1][n]);
    ushort_t* dh = Ho + (size_t)l*DD + (size_t)(nt*64+n)*ND + kt*64 + kc*16;
    *(u32x4*)(dh)     = (u32x4){o[0],o[1],o[2],o[3]};
    *(u32x4*)(dh + 8) = (u32x4){o[4],o[5],o[6],o[7]};
    return;
  }
  int c = (bid - 1030)*256 + t;
  const float4* xr = (const float4*)x;
  float4 v0 = xr[(size_t)c*2], v1 = xr[(size_t)c*2+1];
  u32x4 o = (u32x4){ pk16(v0.x, v0.y), pk16(v0.z, v0.w),
                     pk16(v1.x, v1.y), pk16(v1.z, v1.w) };
  *(u32x4*)(xp + (size_t)c*8) = o;
}

// ---- fp16 MFMA GEMM tile, BK=64, global_load_lds both operands, LDS dbuf,
// XOR-swizzled. 512 threads (8 waves 2x4), wave tile 64x32. ----
#define BKB 128
template<int MODE>
__device__ __forceinline__ void gemm_tile(const ushort_t* __restrict__ A16,
                                          const ushort_t* __restrict__ Wth,
                                          float* __restrict__ C,
                                          unsigned int* __restrict__ hP,
                                          ushort_t* __restrict__ Pbuf,
                                          float* __restrict__ tp4,
                                          const float* __restrict__ a2,
                                          const float* __restrict__ scal,
                                          const int* __restrict__ left,
                                          const int* __restrict__ asp,
                                          const int* __restrict__ tl,
                                          int mtile, int ntile, unsigned char* lds){
  int t = threadIdx.x;
  int m0 = mtile*128, n0 = ntile*128;
  int lane = t & 63, wid = t >> 6;
  int wr = wid >> 2, wcq = wid & 3;
  int lrow = lane & 15, kb = lane >> 4;

  f32x4 acc[4][2];
  #pragma unroll
  for(int mi=0;mi<4;mi++)
    #pragma unroll
    for(int ni=0;ni<2;ni++)
      acc[mi][ni] = (f32x4){0.f,0.f,0.f,0.f};

  int s_row = t >> 3;
  int s_sl  = (t & 7) ^ (s_row & 7);
  int dstoff = wid*1024;

  const ushort_t* Asrc0 = A16 + (size_t)(m0 + s_row)*ND + s_sl*8;
  const ushort_t* Asrc1 = A16 + (size_t)(m0 + 64 + s_row)*ND + s_sl*8;
  const ushort_t* Bsrc0 = Wth + (size_t)(n0 + s_row)*ND + s_sl*8;
  const ushort_t* Bsrc1 = Wth + (size_t)(n0 + 64 + s_row)*ND + s_sl*8;

  GLOAD16(Asrc0, lds + dstoff);
  GLOAD16(Asrc1, lds + 8192 + dstoff);
  GLOAD16(Bsrc0, lds + 16384 + dstoff);
  GLOAD16(Bsrc1, lds + 24576 + dstoff);
  __syncthreads();

  int cur = 0;
  for(int it=0; it<8; ++it){
    if(it < 7){
      int kn = (it+1)*64;
      unsigned char* dst = lds + ((cur^1)<<15);
      GLOAD16(Asrc0 + kn, dst + dstoff);
      GLOAD16(Asrc1 + kn, dst + 8192 + dstoff);
      GLOAD16(Bsrc0 + kn, dst + 16384 + dstoff);
      GLOAD16(Bsrc1 + kn, dst + 24576 + dstoff);
    }
    unsigned char* Ab = lds + (cur<<15);
    unsigned char* Bb = Ab + 16384;
    #pragma unroll
    for(int ks=0; ks<2; ks++){
      f16x8 ah[4], bh[2];
      #pragma unroll
      for(int mi=0;mi<4;mi++){
        int ar = wr*64 + mi*16 + lrow;
        int sl = (ks*4 + kb) ^ (ar & 7);
        ah[mi] = *(const f16x8*)(Ab + ar*BKB + sl*16);
      }
      #pragma unroll
      for(int ni=0;ni<2;ni++){
        int br = wcq*32 + ni*16 + lrow;
        int sl = (ks*4 + kb) ^ (br & 7);
        bh[ni] = *(const f16x8*)(Bb + br*BKB + sl*16);
      }
      #pragma unroll
      for(int mi=0;mi<4;mi++)
        #pragma unroll
        for(int ni=0;ni<2;ni++)
          acc[mi][ni] = __builtin_amdgcn_mfma_f32_16x16x32_f16(ah[mi], bh[ni], acc[mi][ni], 0,0,0);
    }
    __syncthreads();
    cur ^= 1;
  }

  int rg = lane >> 4;
  int cc = lane & 15;
  if(MODE == 0){
    #pragma unroll
    for(int mi=0;mi<4;mi++)
      #pragma unroll
      for(int ni=0;ni<2;ni++){
        int col = n0 + wcq*32 + ni*16 + cc;
        #pragma unroll
        for(int q=0;q<4;q++){
          int row = m0 + wr*64 + mi*16 + rg*4 + q;
          C[(size_t)row*ND + col] = acc[mi][ni][q];
        }
      }
  } else {
    float S0 = scal[0], S1 = scal[1];
    float* CT = (float*)lds;
    int b = m0 >> 8;
    int ibase = m0 & 255;
    {
      float lf=(float)left[b], aspf=(float)asp[b], tlf=(float)tl[b];
      float rrow=lf+aspf-1.f, inv_ctx=1.f/(tlf-aspf);
      #pragma unroll
      for(int mi=0;mi<4;mi++)
        #pragma unroll
        for(int q=0;q<4;q++){
          float jf = (float)(ibase + wr*64 + mi*16 + rg*4 + q);
          float w;
          if(jf < lf)         w = 1.f-(lf-jf)*inv_ctx;
          else if(jf <= rrow) w = 0.f;
          else if(jf < tlf)   w = 1.f-(jf-rrow)*inv_ctx;
          else                w = 0.f;
          acc[mi][0][q] *= w;
          acc[mi][1][q] *= w;
        }
    }
    int tr   = t >> 2;
    int tch  = t & 3;
    float tpsum = 0.f;
    #pragma unroll
    for(int p=0;p<2;p++){
      if((wcq>>1) == p){
        #pragma unroll
        for(int mi=0;mi<4;mi++)
          #pragma unroll
          for(int ni=0;ni<2;ni++)
            #pragma unroll
            for(int q=0;q<4;q++)
              CT[((wcq&1)*32 + ni*16 + cc)*130 + wr*64 + mi*16 + rg*4 + q] = acc[mi][ni][q];
      }
      __syncthreads();
      int lcol = t >> 6;
      int lrow2 = (t & 63)*2;
      #pragma unroll
      for(int u=0;u<8;u++){
        int c = lcol + u*8;
        float2 v2 = *(float2*)&CT[c*130 + lrow2];
        size_t uidx = ((size_t)b*HTB + (size_t)(n0 + p*64 + c)*256 + ibase + lrow2) >> 1;
        hP[uidx] = pk16(v2.x, v2.y);
      }
      {
        int cpr = t & 31;
        int rq  = t >> 5;
        #pragma unroll
        for(int rr2=0; rr2<8; rr2++){
          int row = rq*8 + rr2;
          float pval = S0*CT[(2*cpr)*130 + row] + S1*CT[(2*cpr+1)*130 + row];
          int ig = ibase + row;
          _Float16 ph = (_Float16)pval;
          size_t addr = (size_t)b*65536 + (size_t)(ig>>5)*8192
                      + (size_t)(ig&31)*256 + (n0>>1) + p*32 + cpr;
          Pbuf[addr] = __builtin_bit_cast(unsigned short, ph);
        }
      }
      #pragma unroll
      for(int cc2=0; cc2<16; cc2++){
        int c = tch*16 + cc2;
        tpsum = fmaf(CT[c*130 + tr], a2[n0 + p*64 + c], tpsum);
      }
      __syncthreads();
    }
    tpsum += __shfl_xor(tpsum, 1);
    tpsum += __shfl_xor(tpsum, 2);
    if(tch == 0) tp4[(n0>>7)*32768 + m0 + tr] = tpsum;
  }
}

__global__ __launch_bounds__(512) void k_gemm_t(const ushort_t* __restrict__ A16,
                                                const ushort_t* __restrict__ Wth,
                                                unsigned int* __restrict__ hP,
                                                ushort_t* __restrict__ Pbuf,
                                                float* __restrict__ tp4,
                                                const float* __restrict__ a2,
                                                const float* __restrict__ scal,
                                                const int* __restrict__ left,
                                                const int* __restrict__ asp,
                                                const int* __restrict__ tl){
  __shared__ unsigned char lds[65536];
  int bid = blockIdx.x;
  int ntile = (bid >> 3) & 3;
  int mtile = (bid & 7) | ((bid >> 5) << 3);
  gemm_tile<1>(A16, Wth, nullptr, hP, Pbuf, tp4, a2, scal, left, asp, tl,
               mtile, ntile, lds);
}

__global__ __launch_bounds__(512) void k_gemm_b(const ushort_t* __restrict__ Abase, long aStride,
                                                const ushort_t* __restrict__ Wth,
                                                float* __restrict__ Cbase){
  __shared__ unsigned char lds[65536];
  int l  = blockIdx.x >> 5;
  int tb = blockIdx.x & 31;
  gemm_tile<0>(Abase + (size_t)l*aStride, Wth + (size_t)l*DD,
               Cbase + (size_t)l*MN, nullptr, nullptr, nullptr,
               nullptr, nullptr, nullptr, nullptr, nullptr, tb>>2, tb&3, lds);
}

// layer-0 attention: coalesced fp16-P softmax + MFMA aggregation (B double-buffered).
__global__ __launch_bounds__(256) void k_attn0(
    const ushort_t* __restrict__ hTH,
    const ushort_t* __restrict__ Pbuf,
    const int* __restrict__ adj,
    const float* __restrict__ tpart,
    const int* __restrict__ left, const int* __restrict__ asp, const int* __restrict__ tl,
    ushort_t* __restrict__ h16){
  __shared__ unsigned char attH[32*512];
  __shared__ unsigned char BsH[2][16384];

  int bid = blockIdx.x;
  int b  = bid & 127;
  int ic = bid >> 7;
  int i0 = ic*32;
  int tid = threadIdx.x;
  int lane = tid & 63, w = tid >> 6;
  const ushort_t* HH = hTH + (size_t)b*HTB;
  const ushort_t* Pt = Pbuf + (size_t)b*65536 + (size_t)ic*8192;

  // ---- phase 1: softmax, lanes = j ----
  float t0v=0.f, t1v=0.f, t2v=0.f, t3v=0.f;
  #pragma unroll
  for(int nt=0; nt<4; nt++){
    float4 tv = ((const float4*)(tpart + nt*32768 + b*256))[lane];
    t0v += tv.x; t1v += tv.y; t2v += tv.z; t3v += tv.w;
  }

  for(int rr=0; rr<8; rr++){
    int il = w*8 + rr;
    int i  = i0 + il;
    f16x4v pv = *(const f16x4v*)(Pt + il*256 + lane*4);
    int4 av = ((const int4*)(adj + ((size_t)b*NLQ + i)*NLQ))[lane];
    float e0 = fmaxf((float)pv[0] + t0v, 0.f);
    float e1 = fmaxf((float)pv[1] + t1v, 0.f);
    float e2 = fmaxf((float)pv[2] + t2v, 0.f);
    float e3 = fmaxf((float)pv[3] + t3v, 0.f);
    float m = -3.0e38f;
    if(av.x>0) m = e0;
    if(av.y>0) m = fmaxf(m, e1);
    if(av.z>0) m = fmaxf(m, e2);
    if(av.w>0) m = fmaxf(m, e3);
    m = wave_max(m);
    float p0 = (av.x>0) ? __expf(e0-m) : 0.f;
    float p1 = (av.y>0) ? __expf(e1-m) : 0.f;
    float p2 = (av.z>0) ? __expf(e2-m) : 0.f;
    float p3 = (av.w>0) ? __expf(e3-m) : 0.f;
    float s = wave_sum(p0+p1+p2+p3);
    float inv = 1.f/s;
    unsigned int w0 = pk16(p0*inv, p1*inv);
    unsigned int w1 = pk16(p2*inv, p3*inv);
    int off = il*512 + ((lane*8) ^ ((il&7)<<4));
    *(u32x2*)(attH + off) = (u32x2){w0,w1};
  }

  // ---- phase 2: O[i][d] = att @ h via MFMA; B double-buffered gload_lds ----
  int wm = w >> 1, wn = w & 1;
  int lrow = lane & 15, kb = lane >> 4;
  int rg = lane >> 4, cc = lane & 15;
  float lf=(float)left[b], aspf=(float)asp[b], tlf=(float)tl[b];
  float rrv=lf+aspf-1.f, ctx=tlf-aspf;
  int arow = wm*16 + lrow;
  int aswz = (arow&7)<<4;

  {
    #pragma unroll
    for(int u=0;u<4;u++){
      int chunk = (u*4 + w)*64 + lane;
      int row = chunk >> 2, sl = chunk & 3;
      GLOAD16(HH + (size_t)row*256 + sl*8, BsH[0] + (u*4+w)*1024);
    }
  }
  __syncthreads();

  int tt = 0;
  for(int dp=0; dp<2; dp++){
    int d0 = dp*256;
    f32x4 acc[8];
    #pragma unroll
    for(int ni=0;ni<8;ni++) acc[ni] = (f32x4){0.f,0.f,0.f,0.f};
    for(int ks=0; ks<8; ks++){
      if(tt < 15){
        int nt2 = tt + 1;
        int dpp = nt2 >> 3, kss = nt2 & 7;
        int dn = dpp*256, jn = kss*32;
        #pragma unroll
        for(int u=0;u<4;u++){
          int chunk = (u*4 + w)*64 + lane;
          int row = chunk >> 2, sl = chunk & 3;
          GLOAD16(HH + (size_t)(dn+row)*256 + jn + sl*8, BsH[nt2&1] + (u*4+w)*1024);
        }
      }
      int j0 = ks*32;
      const unsigned char* Bb = BsH[tt&1];
      int aoff = arow*512 + ((j0*2 + kb*16) ^ aswz);
      f16x8 ah = *(const f16x8*)(attH + aoff);
      #pragma unroll
      for(int ni=0; ni<8; ni++){
        f16x8 bh = *(const f16x8*)(Bb + (wn*128 + ni*16 + lrow)*64 + kb*16);
        acc[ni] = __builtin_amdgcn_mfma_f32_16x16x32_f16(ah, bh, acc[ni], 0,0,0);
      }
      __syncthreads();
      tt++;
    }
    #pragma unroll
    for(int q=0;q<4;q++){
      int row = i0 + wm*16 + rg*4 + q;
      float fi = (float)row;
      float wgt;
      if(fi < lf)        wgt = 1.f-(lf-fi)/ctx;
      else if(fi <= rrv) wgt = 0.f;
      else if(fi < tlf)  wgt = 1.f-(fi-rrv)/ctx;
      else               wgt = 0.f;
      #pragma unroll
      for(int ni=0;ni<8;ni++){
        int col = d0 + wn*128 + ni*16 + cc;
        float ov = wgt*fmaxf(acc[ni][q], 0.f);
        h16[((size_t)b*NLQ + row)*ND + col] =
            __builtin_bit_cast(unsigned short, (_Float16)ov);
      }
    }
  }
}

// T[l][b*256+j] = h1[b,j,:] . v_l   (h1 fp16)
__global__ __launch_bounds__(256) void k_tv(const ushort_t* __restrict__ h16,
                                            const float* __restrict__ v,
                                            float* __restrict__ T){
  int row  = blockIdx.x*4 + (threadIdx.x>>6);
  int lane = threadIdx.x & 63;
  f16x8 hv = *(const f16x8*)(h16 + (size_t)row*ND + lane*8);
  float hf[8];
  #pragma unroll
  for(int i=0;i<8;i++) hf[i] = (float)hv[i];
  float s0,s1,s2,s3,s4;
  #define DOTV(SL, L) { \
    const float4* vr = (const float4*)(v + (L)*ND); \
    float4 v0 = vr[lane*2], v1 = vr[lane*2+1]; \
    float dd = hf[0]*v0.x+hf[1]*v0.y+hf[2]*v0.z+hf[3]*v0.w \
             + hf[4]*v1.x+hf[5]*v1.y+hf[6]*v1.z+hf[7]*v1.w; \
    SL = wave_sum(dd); }
  DOTV(s0,0) DOTV(s1,1) DOTV(s2,2) DOTV(s3,3) DOTV(s4,4)
  #undef DOTV
  if(lane==0){
    T[0*32768 + row]=s0; T[1*32768 + row]=s1; T[2*32768 + row]=s2;
    T[3*32768 + row]=s3; T[4*32768 + row]=s4;
  }
}

// R16[b*8+k,:] = h16[b, l0+k, :] or 0 (straight fp16 copy)
__global__ __launch_bounds__(256) void k_rows(const ushort_t* __restrict__ h16,
                                              const int* __restrict__ left, const int* __restrict__ asp,
                                              ushort_t* __restrict__ R){
  int b = blockIdx.x;
  int nk = asp[b], l0 = left[b];
  const unsigned int* src = (const unsigned int*)(h16 + (size_t)b*NLQ*ND);
  unsigned int* dst = (unsigned int*)(R + (size_t)b*8*ND);
  #pragma unroll
  for(int u=0; u<8; u++){
    int idx = threadIdx.x + u*256;
    int k = idx >> 8, c = idx & 255;
    dst[idx] = (k<nk) ? src[(size_t)(l0+k)*256 + c] : 0u;
  }
}

// one block per (layer, batch): 5 aspect-row atts + y16 = fp16(att @ h1).
__global__ __launch_bounds__(256) void k_att5(const ushort_t* __restrict__ h16,
    const float* __restrict__ Hasp, const float* __restrict__ T,
    const int* __restrict__ adj, const float* __restrict__ scal,
    const int* __restrict__ left, const int* __restrict__ asp,
    ushort_t* __restrict__ y){
  __shared__ float att[5][260];
  int b  = blockIdx.x & 127;
  int l  = blockIdx.x >> 7;
  int tid = threadIdx.x, lane = tid&63, w = tid>>6;
  int nk = asp[b], l0 = left[b];
  float S0 = scal[2*(l+1)], S1 = scal[2*(l+1)+1];

  for(int k = w; k < 5; k += 4){
    if(k < nk){
      const float2* hrow = (const float2*)(Hasp + (size_t)l*MN + (size_t)(b*8+k)*ND);
      const int* arow = adj + ((size_t)b*NLQ + (l0+k))*NLQ;
      const float* Tl = T + l*32768 + b*256;
      float e[4]; int av[4];
      float m = -3.0e38f;
      #pragma unroll
      for(int q=0;q<4;q++){
        int j = lane + 64*q;
        float2 hp = hrow[j];
        av[q] = arow[j];
        e[q] = fmaxf(S0*hp.x + S1*hp.y + Tl[j], 0.f);
        if(av[q] > 0) m = fmaxf(m, e[q]);
      }
      m = wave_max(m);
      float pp[4]; float s = 0.f;
      #pragma unroll
      for(int q=0;q<4;q++){
        pp[q] = (av[q] > 0) ? __expf(e[q]-m) : 0.f;
        s += pp[q];
      }
      s = wave_sum(s);
      float inv = 1.f/s;
      #pragma unroll
      for(int q=0;q<4;q++) att[k][lane+64*q] = pp[q]*inv;
    } else {
      #pragma unroll
      for(int q=0;q<4;q++) att[k][lane+64*q] = 0.f;
    }
  }
  __syncthreads();

  int d = tid;
  const ushort_t* hb = h16 + (size_t)b*NLQ*ND;
  float ax[5] = {0,0,0,0,0}, ay[5] = {0,0,0,0,0};
  for(int jj=0; jj<NLQ; jj++){
    float hx = f16u(hb[(size_t)jj*ND + d]);
    float hy = f16u(hb[(size_t)jj*ND + 256 + d]);
    #pragma unroll
    for(int k=0;k<5;k++){
      float a = att[k][jj];
      ax[k] += a*hx;
      ay[k] += a*hy;
    }
  }
  ushort_t* yb = y + (size_t)l*MN + (size_t)b*8*ND;
  #pragma unroll
  for(int k=0;k<5;k++){
    yb[(size_t)k*ND + d]       = __builtin_bit_cast(unsigned short, (_Float16)ax[k]);
    yb[(size_t)k*ND + 256 + d] = __builtin_bit_cast(unsigned short, (_Float16)ay[k]);
  }
  #pragma unroll
  for(int u=0;u<6;u++) yb[5*ND + u*256 + tid] = 0;
}

__global__ __launch_bounds__(256) void k_g(const float* __restrict__ hp,
    const int* __restrict__ asp, float* __restrict__ g){
  int b = blockIdx.x, d = threadIdx.x;
  int nk = asp[b];
  float gx=0.f, gy=0.f;
  for(int l=0;l<5;l++){
    for(int k=0;k<nk;k++){
      const float* r = hp + (size_t)l*MN + (size_t)(b*8+k)*ND;
      gx += fmaxf(r[d], 0.f);
      gy += fmaxf(r[d+256], 0.f);
    }
  }
  g[b*ND + d]       = 0.2f*gx;
  g[b*ND + 256 + d] = 0.2f*gy;
}

// s[b,m] = g[b,:] . x16[b,m,:]
__global__ __launch_bounds__(256) void k_dot(const ushort_t* __restrict__ x16,
    const float* __restrict__ g, float* __restrict__ s){
  int row  = blockIdx.x*4 + (threadIdx.x>>6);
  int b    = row >> 8;
  int lane = threadIdx.x & 63;
  f16x8 xv = *(const f16x8*)(x16 + (size_t)row*ND + lane*8);
  const float4* gr = (const float4*)(g + (size_t)b*ND);
  float4 g0 = gr[lane*2], g1 = gr[lane*2+1];
  float d = (float)xv[0]*g0.x + (float)xv[1]*g0.y + (float)xv[2]*g0.z + (float)xv[3]*g0.w
          + (float)xv[4]*g1.x + (float)xv[5]*g1.y + (float)xv[6]*g1.z + (float)xv[7]*g1.w;
  d = wave_sum(d);
  if(lane==0) s[row] = d;
}

__global__ __launch_bounds__(256) void k_out(const ushort_t* __restrict__ x16,
    const float* __restrict__ s, float* __restrict__ out){
  int b  = blockIdx.x >> 2;
  int ch = blockIdx.x & 3;
  int tid = threadIdx.x, lane = tid&63, w = tid>>6;
  __shared__ float red[4];
  __shared__ float alpha[NLQ];
  __shared__ float part[128];
  float sv = s[b*NLQ + tid];
  float m = wave_max(sv);
  if(lane==0) red[w] = m;
  __syncthreads();
  m = fmaxf(fmaxf(red[0],red[1]), fmaxf(red[2],red[3]));
  float p = __expf(sv - m);
  float su = wave_sum(p);
  __syncthreads();
  if(lane==0) red[w] = su;
  __syncthreads();
  su = red[0]+red[1]+red[2]+red[3];
  alpha[tid] = p/su;
  __syncthreads();
  int d = ch*128 + (tid & 127);
  int half = tid >> 7;
  const ushort_t* xb = x16 + (size_t)b*NLQ*ND;
  float acc = 0.f;
  for(int mm = half*128; mm < half*128 + 128; mm++)
    acc += alpha[mm] * f16u(xb[(size_t)mm*ND + d]);
  if(half) part[tid & 127] = acc;
  __syncthreads();
  if(!half) out[(size_t)b*ND + d] = acc + part[tid & 127];
}

extern "C" void kernel_launch(void* const* d_in, const int* in_sizes, int n_in,
                              void* d_out, int out_size, void* d_ws, size_t ws_size,
                              hipStream_t stream){
  const float* x    = (const float*)d_in[0];
  const float* Wst  = (const float*)d_in[1];
  const float* ast  = (const float*)d_in[2];
  const int*   adj  = (const int*)d_in[3];
  const int*   left = (const int*)d_in[4];
  const int*   asp  = (const int*)d_in[5];
  const int*   tl   = (const int*)d_in[6];
  float* out = (float*)d_out;
  float* ws  = (float*)d_ws;

  const size_t SZ = (size_t)NB*NLQ*ND;   // 16.78M floats
  float* bufA = ws;
  float* bufB = ws + SZ;
  float* ws2  = ws + 2*SZ;
  float* tpart= ws2;                     // 4*32768
  float* T    = tpart + 4*32768;         // 163840
  float* g    = T + 163840;              // 65536
  float* scal = g + 65536;               // 16
  float* v    = scal + 16;               // 2560
  float* sbuf = v + 2560;                // 32768
  ushort_t* w0th = (ushort_t*)(sbuf + 32768);  // DD ushorts

  // bufA: Pbuf [0, 8.39M ushorts) | h16 [8.39M, 25.2M) | wt15h [25.2M, 26.5M)
  ushort_t* Pbuf = (ushort_t*)bufA;
  ushort_t* h16  = Pbuf + (size_t)NB*65536;
  ushort_t* wt15h = h16 + (size_t)NB*NLQ*ND;   // SAFE: never clobbered

  // bufB: hT plane [0, 8.39M floats) / x16 [8.39M, 16.78M floats)
  ushort_t* hTH  = (ushort_t*)bufB;
  ushort_t* x16  = (ushort_t*)(bufB + (SZ>>1));

  float* Hasp = bufB;                                // reuse after attn0
  ushort_t* y16 = (ushort_t*)(Hasp + (size_t)5*MN);
  float* hpF  = bufB + (size_t)5*MN + (size_t)5*MN/2;
  ushort_t* R16 = (ushort_t*)(hpF + (size_t)5*MN);

  // merged prologue: scal(6) | wa2(640) | wcvt l0(64) | wcvt l1-5(320) | xcvt(8192)
  k_prep<<<9222, 256, 0, stream>>>(Wst, ast, x, scal, v, w0th, wt15h, x16);

  // layer 0: fp16 GEMM; posw in epilogue; emits plane + compact P + t-partials
  k_gemm_t<<<(NB*NLQ/128)*(ND/128), 512, 0, stream>>>(x16, w0th,
      (unsigned int*)hTH, Pbuf, tpart, ast + ND, scal, left, asp, tl);
  k_attn0<<<NB*8, 256, 0, stream>>>(hTH, Pbuf, adj, tpart, left, asp, tl, h16);

  // layers 1..5 on aspect rows only
  k_tv<<<NB*NLQ/4, 256, 0, stream>>>(h16, v, T);
  k_rows<<<NB, 256, 0, stream>>>(h16, left, asp, R16);
  k_gemm_b<<<5*32, 512, 0, stream>>>(R16, 0L, wt15h, Hasp);
  k_att5<<<5*NB, 256, 0, stream>>>(h16, Hasp, T, adj, scal, left, asp, y16);
  k_gemm_b<<<5*32, 512, 0, stream>>>(y16, (long)MN, wt15h, hpF);
  k_g<<<NB, 256, 0, stream>>>(hpF, asp, g);

  // final attention over original x (fp16 copy)
  k_dot<<<NB*NLQ/4, 256, 0, stream>>>(x16, g, sbuf);
  k_out<<<NB*4, 256, 0, stream>>>(x16, sbuf, out);
}